// Round 5
// baseline (457.512 us; speedup 1.0000x reference)
//
#include <hip/hip_runtime.h>
#include <hip/hip_bf16.h>
#include <math.h>

#define ACT_SHIFT_F (-13.8155095579637744f)
#define GRID_VOX 4096000
#define GP_BYTES  (GRID_VOX * 32)          // fp16 x16 slots per voxel
#define W0P_OFF   GP_BYTES                 // 8 frags  * 1024B
#define W1P_OFF   (W0P_OFF + 8 * 1024)     // 32 frags * 1024B
#define W2P_OFF   (W1P_OFF + 32 * 1024)    // 4 frags  * 1024B
#define WS_NEED   ((size_t)(W2P_OFF + 4 * 1024))

typedef _Float16 f16x8 __attribute__((ext_vector_type(8)));
typedef _Float16 h2    __attribute__((ext_vector_type(2)));
typedef float    f32x4 __attribute__((ext_vector_type(4)));
typedef float    fv4   __attribute__((ext_vector_type(4)));  // clang vector (nontemporal-ok)

// f32 pair -> packed fp16 dword (RNE via v_cvt_f16_f32)
__device__ __forceinline__ unsigned int pkh2(float a, float b) {
    h2 v; v.x = (_Float16)a; v.y = (_Float16)b;
    return __builtin_bit_cast(unsigned int, v);
}
__device__ __forceinline__ unsigned short f2h(float x) {
    _Float16 h = (_Float16)x; return __builtin_bit_cast(unsigned short, h);
}

// ---------------- repack (fused): grid -> interleaved fp16 [vox][16]; W -> B-frags ----
// Slot order: 0..11 = k0 channels, 12..14 = 0, 15 = density (so phase A's X-row
// stores are dword-aligned and density rides the pad slot).
__global__ void repack_all(const float* __restrict__ dens, const float* __restrict__ k0,
                           const float* __restrict__ w0, const float* __restrict__ w1,
                           const float* __restrict__ w2,
                           unsigned short* __restrict__ gp, unsigned short* __restrict__ wp)
{
    const int b = blockIdx.x;
    if (b < 4000) {
        const int v4 = b * 1024 + threadIdx.x * 4;       // 4 consecutive voxels
        const fv4 d4 = __builtin_nontemporal_load((const fv4*)(dens + v4));
        fv4 c4[12];
        #pragma unroll
        for (int c = 0; c < 12; ++c)
            c4[c] = __builtin_nontemporal_load((const fv4*)(k0 + (size_t)c * GRID_VOX + v4));
        uint4* dst = (uint4*)(gp + (size_t)v4 * 16);
        #pragma unroll
        for (int j = 0; j < 4; ++j) {
            const float* cj = &((const float*)c4)[j];     // c4[c] component j at cj[4*c]
            uint4 q0, q1;
            q0.x = pkh2(cj[4*0],  cj[4*1]);
            q0.y = pkh2(cj[4*2],  cj[4*3]);
            q0.z = pkh2(cj[4*4],  cj[4*5]);
            q0.w = pkh2(cj[4*6],  cj[4*7]);
            q1.x = pkh2(cj[4*8],  cj[4*9]);
            q1.y = pkh2(cj[4*10], cj[4*11]);
            q1.z = 0u;                        // slots 12,13
            q1.w = pkh2(0.f, d4[j]);          // slot 14 = 0, slot 15 = density
            dst[j*2 + 0] = q0;
            dst[j*2 + 1] = q1;
        }
        return;
    }
    // ---- weight repack: B-frag (16x16x32): lane l holds B[k=(l>>4)*8+j][n=l&15] ----
    const int t = (b - 4000) * 256 + threadIdx.x;
    if (t >= 44 * 64) return;
    const int f = t >> 6, l = t & 63;
    const int n16 = l & 15, kg = l >> 4;
    unsigned short v[8];
    if (f < 8) {                       // W0: ntile=f, K=32 (feature rows 0..11 real)
        const int n = f * 16 + n16;
        #pragma unroll
        for (int j = 0; j < 8; ++j) {
            const int k = kg * 8 + j;
            v[j] = (k < 12) ? f2h(w0[k * 128 + n]) : (unsigned short)0;
        }
    } else if (f < 40) {               // W1: frag (nt, ks)
        const int ff = f - 8, nt = ff >> 2, ks = ff & 3;
        const int n = nt * 16 + n16;
        #pragma unroll
        for (int j = 0; j < 8; ++j) {
            const int k = ks * 32 + kg * 8 + j;
            v[j] = f2h(w1[k * 128 + n]);
        }
    } else {                           // W2: N=16 (cols 0..2 real), frag ks
        const int ks = f - 40;
        #pragma unroll
        for (int j = 0; j < 8; ++j) {
            const int k = ks * 32 + kg * 8 + j;
            v[j] = (n16 < 3) ? f2h(w2[k * 3 + n16]) : (unsigned short)0;
        }
    }
    uint4 q;
    q.x = v[0] | (v[1] << 16); q.y = v[2] | (v[3] << 16);
    q.z = v[4] | (v[5] << 16); q.w = v[6] | (v[7] << 16);
    *(uint4*)(wp + f * 512 + l * 8) = q;
}

// voxel-corner offsets (in voxel units; *2 applied at use site for uint4 pairs)
#define OFF_C0 0
#define OFF_C1 1
#define OFF_C2 160
#define OFF_C3 161
#define OFF_C4 25600
#define OFF_C5 25601
#define OFF_C6 25760
#define OFF_C7 25761

// issue the 8 corner loads for chunk CK into named regs pq0..pq7
#define ISSUE_GATHER(CK) do {                                                        \
    const int s_ = (CK) * 128 + sl;                                                  \
    const float tp_ = 0.05f + (1.95f / 255.f) * (float)s_;                           \
    const float px_ = ox + vx*tp_, py_ = oy + vy*tp_, pz_ = oz + vz*tp_;             \
    inbox_p = (px_ >= -1.f) & (px_ <= 1.f) & (py_ >= -1.f) & (py_ <= 1.f) &          \
              (pz_ >= -1.f) & (pz_ <= 1.f);                                          \
    if (inbox_p) {                                                                   \
        const float ix_ = fminf(fmaxf((px_ + 1.f) * 79.5f, 0.f), 159.f);             \
        const float iy_ = fminf(fmaxf((py_ + 1.f) * 79.5f, 0.f), 159.f);             \
        const float iz_ = fminf(fmaxf((pz_ + 1.f) * 79.5f, 0.f), 159.f);             \
        const int x0_ = min((int)ix_, 158), y0_ = min((int)iy_, 158),                \
                  z0_ = min((int)iz_, 158);                                          \
        const size_t b_ = (size_t)((x0_ * 160 + y0_) * 160 + z0_) * 2 + hf;          \
        pq0 = gq[b_ + OFF_C0*2]; pq1 = gq[b_ + OFF_C1*2];                            \
        pq2 = gq[b_ + OFF_C2*2]; pq3 = gq[b_ + OFF_C3*2];                            \
        pq4 = gq[b_ + OFF_C4*2]; pq5 = gq[b_ + OFF_C5*2];                            \
        pq6 = gq[b_ + OFF_C6*2]; pq7 = gq[b_ + OFF_C7*2];                            \
    }                                                                                \
} while (0)

// ---------------- main render: one block per ray ----------------
// Changes vs prior round (VALU-cut levers; r4 showed VALUBusy 51% is the top pipe):
//  - whole pipeline fp16 (grid/X/H/weights), MFMA 16x16x32_f16: phase-A trilerp is
//    4 v_pk_fma_f16 per corner directly on loaded pairs — no unpack shifts at all
//    (~190 -> ~40 VALU/thread/chunk). fp16 is strictly more precise than bf16 here.
//  - density rides grid slot 15; alpha computed by hf==1; X-row stores dword-aligned.
//  - bias folded into MFMA C-operand init (acc = {bias,...}).
//  - L0/L1 weight prefetch as even/odd named double-buffer (no register rotate).
__global__ __launch_bounds__(256, 3)
void dvgo_mfma(const float* __restrict__ rays_o, const float* __restrict__ rays_d,
               const float* __restrict__ w0, const float* __restrict__ b0,
               const float* __restrict__ b1, const float* __restrict__ b2,
               const unsigned short* __restrict__ gp,   // packed grid
               const unsigned short* __restrict__ wpk,  // packed weights
               float* __restrict__ out)
{
    __shared__ unsigned short XH[128 * 136]; // union: Xs[128][40] / Hs[128][136]
    __shared__ float shA[128];                // per-chunk (1-alpha)
    __shared__ float wts[128];                // alpha, then final weights
    __shared__ float b0eff[128];
    __shared__ float b1s[128];
    __shared__ float vemb[28];
    __shared__ float red[4][3];
    __shared__ float b2s[3];
    __shared__ float Tcs[3];                  // carry: T before chunk ck; Tcs[2]=ainv
    __shared__ float spart;                   // wave0 scan total

    const int r = blockIdx.x, t = threadIdx.x;
    const int l = t & 63, wv = t >> 6;
    const int col = l & 15, rg = l >> 4;
    const int sl = t >> 1, hf = t & 1;

    const float ox = rays_o[r*3+0], oy = rays_o[r*3+1], oz = rays_o[r*3+2];
    const float dxr = rays_d[r*3+0], dyr = rays_d[r*3+1], dzr = rays_d[r*3+2];
    const float rn = rsqrtf(dxr*dxr + dyr*dyr + dzr*dzr);
    const float vx = dxr*rn, vy = dyr*rn, vz = dzr*rn;

    const uint4* gq = (const uint4*)gp;
    _Float16* XHh = (_Float16*)XH;

    // ---- prefetched gather state (named regs, held across the MLP) ----
    uint4 pq0, pq1, pq2, pq3, pq4, pq5, pq6, pq7;
    bool inbox_p = false;

    ISSUE_GATHER(0);   // chunk-0 gathers fly during the setup phase below

    // ---- phase 0: vemb, biases ----
    if (t < 27) {
        float val;
        if (t < 3) val = (t == 0) ? vx : ((t == 1) ? vy : vz);
        else {
            int q = t - 3;
            const bool is_sin = q < 12;
            if (!is_sin) q -= 12;
            const int i = q >> 2, p = q & 3;
            const float a = ((i == 0) ? vx : ((i == 1) ? vy : vz)) * (float)(1 << p);
            val = is_sin ? sinf(a) : cosf(a);
        }
        vemb[t] = val;
    }
    if (t < 3)   b2s[t] = b2[t];
    if (t < 128) b1s[t] = b1[t];
    if (t == 0)  Tcs[0] = 1.f;
    __syncthreads();

    if (t < 128) {                       // fold view embedding into layer-0 bias
        float a = b0[t];
        #pragma unroll
        for (int k = 0; k < 27; ++k) a = fmaf(vemb[k], w0[(12 + k) * 128 + t], a);
        b0eff[t] = a;
    }

    const unsigned short* w0p = wpk;
    const unsigned short* w1p = wpk + 8 * 512;
    const unsigned short* w2p = wpk + 40 * 512;

    float pacc = 0.f;   // per-lane weighted-rgb accumulator (cols 0..2 meaningful)

    #pragma unroll 1
    for (int ck = 0; ck < 2; ++ck) {
        // ---- phase A: consume prefetched gathers -> X rows, alpha ----
        {
            unsigned int* xd = (unsigned int*)&XH[sl * 40];
            if (inbox_p) {
                // recompute trilerp fractions (cheap; avoids holding w8 across MLP)
                const int s = ck * 128 + sl;
                const float tp = 0.05f + (1.95f / 255.f) * (float)s;
                const float px = ox + vx*tp, py = oy + vy*tp, pz = oz + vz*tp;
                const float ix = fminf(fmaxf((px + 1.f) * 79.5f, 0.f), 159.f);
                const float iy = fminf(fmaxf((py + 1.f) * 79.5f, 0.f), 159.f);
                const float iz = fminf(fmaxf((pz + 1.f) * 79.5f, 0.f), 159.f);
                const int x0 = min((int)ix, 158), y0 = min((int)iy, 158), z0 = min((int)iz, 158);
                const float fx = ix - x0, fy = iy - y0, fz = iz - z0;
                const float gx = 1.f - fx, gy = 1.f - fy, gz = 1.f - fz;
                float w8[8];
                w8[0]=gx*gy*gz; w8[1]=gx*gy*fz; w8[2]=gx*fy*gz; w8[3]=gx*fy*fz;
                w8[4]=fx*gy*gz; w8[5]=fx*gy*fz; w8[6]=fx*fy*gz; w8[7]=fx*fy*fz;
                h2 ah0 = {0, 0}, ah1 = {0, 0}, ah2 = {0, 0}, ah3 = {0, 0};
                #define CONSUME(Q, WI) {                                             \
                    h2 wc2; wc2.x = (_Float16)w8[WI]; wc2.y = wc2.x;                 \
                    ah0 += __builtin_bit_cast(h2, (Q).x) * wc2;                      \
                    ah1 += __builtin_bit_cast(h2, (Q).y) * wc2;                      \
                    ah2 += __builtin_bit_cast(h2, (Q).z) * wc2;                      \
                    ah3 += __builtin_bit_cast(h2, (Q).w) * wc2;                      \
                }
                CONSUME(pq0, 0); CONSUME(pq1, 1); CONSUME(pq2, 2); CONSUME(pq3, 3);
                CONSUME(pq4, 4); CONSUME(pq5, 5); CONSUME(pq6, 6); CONSUME(pq7, 7);
                #undef CONSUME
                if (hf == 0) {   // slots 0..7 = feat0..7 -> X cols 0..7
                    xd[0] = __builtin_bit_cast(unsigned int, ah0);
                    xd[1] = __builtin_bit_cast(unsigned int, ah1);
                    xd[2] = __builtin_bit_cast(unsigned int, ah2);
                    xd[3] = __builtin_bit_cast(unsigned int, ah3);
                } else {         // slots 8..15 = feat8..11, 0,0,0, dens
                    xd[4] = __builtin_bit_cast(unsigned int, ah0);
                    xd[5] = __builtin_bit_cast(unsigned int, ah1);
                    xd[6] = 0u;                    // cols 12,13
                    xd[7] = 0u;                    // cols 14,15 (NOT dens)
                    const float dv = (float)ah3.y; // slot 15 = density trilerp
                    const float e = expf(dv + ACT_SHIFT_F);
                    const float op = 1.f + e;
                    const float alpha = e / (op + sqrtf(op));   // 1-(1+e)^(-1/2)
                    wts[sl] = alpha;
                    shA[sl] = 1.f - alpha;
                }
            } else {
                if (hf == 0) {
                    xd[0]=0u; xd[1]=0u; xd[2]=0u; xd[3]=0u;
                } else {
                    xd[4]=0u; xd[5]=0u; xd[6]=0u; xd[7]=0u;
                    wts[sl] = 0.f;
                    shA[sl] = 1.f;
                }
            }
            // zero pad cols 16..31 (K=32 tail) — every chunk (union leaves Hs bytes)
            if (hf == 0) { xd[8]=0u;  xd[9]=0u;  xd[10]=0u; xd[11]=0u; }
            else         { xd[12]=0u; xd[13]=0u; xd[14]=0u; xd[15]=0u; }
            if (ck == 0) ISSUE_GATHER(1);   // chunk-1 loads hide under scan + MLP
        }
        __syncthreads();   // Xs/shA/alpha complete

        const int row0 = wv * 32;   // this wave owns sample-rows [row0, row0+32)

        // ---- A0 fragment preload: MUST precede the next barrier (Xs dies here;
        //      Hs writes below would otherwise clobber other waves' unread Xs rows)
        f16x8 A0[2];
        #pragma unroll
        for (int mt = 0; mt < 2; ++mt)
            A0[mt] = *(const f16x8*)(&XH[(row0 + mt * 16 + col) * 40 + rg * 8]);

        // ---- transmittance scan (threads 0..127 = waves 0,1), carry Tcs[ck] ----
        float v = 1.f;
        if (t < 128) {
            v = shA[t];
            #pragma unroll
            for (int off = 1; off < 64; off <<= 1) {
                const float u = __shfl_up(v, off);
                if (l >= off) v *= u;
            }
            if (wv == 0 && l == 63) spart = v;
        }
        __syncthreads();   // spart visible; also: all waves' A0 loads complete
        if (t < 128) {     // scan tail (waves 0-1); waves 2-3 fall through to L0
            float excl = __shfl_up(v, 1);
            if (l == 0) excl = 1.f;
            float E = Tcs[ck];
            const float sp = spart;
            if (wv == 1) E *= sp;
            const float w = wts[t] * E * excl;
            wts[t] = w;
            if (t == 127) Tcs[ck + 1] = Tcs[ck] * sp * v;
        }
        // (no barrier here: wts not read until L2 epilogue; Hs rows wave-private)

        // ---- layer 0: H0 = relu(X*W0 + b0eff), K=32; even/odd B prefetch ----
        {
            #define L0_STEP(B, NT) {                                                  \
                const float bias = b0eff[(NT) * 16 + col];                            \
                _Pragma("unroll")                                                     \
                for (int mt = 0; mt < 2; ++mt) {                                      \
                    f32x4 acc = {bias, bias, bias, bias};                             \
                    acc = __builtin_amdgcn_mfma_f32_16x16x32_f16(A0[mt], B, acc, 0, 0, 0); \
                    _Pragma("unroll")                                                 \
                    for (int q = 0; q < 4; ++q) {                                     \
                        const float vv = fmaxf(acc[q], 0.f);                          \
                        const int row = row0 + mt * 16 + rg * 4 + q;                  \
                        XHh[row * 136 + (NT) * 16 + col] = (_Float16)vv;              \
                    }                                                                 \
                }                                                                     \
            }
            f16x8 Ba = *(const f16x8*)(w0p + l * 8);
            #pragma unroll 1
            for (int nt = 0; nt < 8; nt += 2) {
                const f16x8 Bb = *(const f16x8*)(w0p + (nt + 1) * 512 + l * 8);
                L0_STEP(Ba, nt);
                if (nt < 6) Ba = *(const f16x8*)(w0p + (nt + 2) * 512 + l * 8);
                L0_STEP(Bb, nt + 1);
            }
            #undef L0_STEP
        }

        // ---- W2 fragment hoist: issue now, consumed after L1 (latency hidden) ----
        f16x8 W2k[4];
        #pragma unroll
        for (int ks = 0; ks < 4; ++ks)
            W2k[ks] = *(const f16x8*)(w2p + ks * 512 + l * 8);

        // ---- layer 1: H1 = relu(H0*W1 + b1), K=128, in-place, even/odd prefetch ----
        {
            f16x8 A1[2][4];
            #pragma unroll
            for (int mt = 0; mt < 2; ++mt)
                #pragma unroll
                for (int ks = 0; ks < 4; ++ks)
                    A1[mt][ks] = *(const f16x8*)(&XH[(row0 + mt * 16 + col) * 136 + ks * 32 + rg * 8]);
            #define L1_STEP(BK, NT) {                                                 \
                const float bias = b1s[(NT) * 16 + col];                              \
                _Pragma("unroll")                                                     \
                for (int mt = 0; mt < 2; ++mt) {                                      \
                    f32x4 acc = {bias, bias, bias, bias};                             \
                    _Pragma("unroll")                                                 \
                    for (int ks = 0; ks < 4; ++ks)                                    \
                        acc = __builtin_amdgcn_mfma_f32_16x16x32_f16(A1[mt][ks], BK[ks], acc, 0, 0, 0); \
                    _Pragma("unroll")                                                 \
                    for (int q = 0; q < 4; ++q) {                                     \
                        const float vv = fmaxf(acc[q], 0.f);                          \
                        const int row = row0 + mt * 16 + rg * 4 + q;                  \
                        XHh[row * 136 + (NT) * 16 + col] = (_Float16)vv;              \
                    }                                                                 \
                }                                                                     \
            }
            f16x8 BkA[4], BkB[4];
            #pragma unroll
            for (int ks = 0; ks < 4; ++ks)
                BkA[ks] = *(const f16x8*)(w1p + ks * 512 + l * 8);
            #pragma unroll 1
            for (int nt = 0; nt < 8; nt += 2) {
                #pragma unroll
                for (int ks = 0; ks < 4; ++ks)
                    BkB[ks] = *(const f16x8*)(w1p + ((nt + 1) * 4 + ks) * 512 + l * 8);
                L1_STEP(BkA, nt);
                if (nt < 6) {
                    #pragma unroll
                    for (int ks = 0; ks < 4; ++ks)
                        BkA[ks] = *(const f16x8*)(w1p + ((nt + 2) * 4 + ks) * 512 + l * 8);
                }
                L1_STEP(BkB, nt + 1);
            }
            #undef L1_STEP
        }

        __syncthreads();   // wts (scan tail) visible to all waves; Hs wave-private

        // ---- layer 2 + epilogue: rgb = sigmoid(H1*W2 + b2); pacc += wts*rgb ----
        {
            const float bias2 = (col < 3) ? b2s[col] : 0.f;
            #pragma unroll
            for (int mt = 0; mt < 2; ++mt) {
                f16x8 A2[4];
                #pragma unroll
                for (int ks = 0; ks < 4; ++ks)
                    A2[ks] = *(const f16x8*)(&XH[(row0 + mt * 16 + col) * 136 + ks * 32 + rg * 8]);
                f32x4 acc = {bias2, bias2, bias2, bias2};
                #pragma unroll
                for (int ks = 0; ks < 4; ++ks)
                    acc = __builtin_amdgcn_mfma_f32_16x16x32_f16(A2[ks], W2k[ks], acc, 0, 0, 0);
                #pragma unroll
                for (int q = 0; q < 4; ++q) {
                    const float sg = 1.f / (1.f + expf(-acc[q]));
                    const int srow = row0 + mt * 16 + rg * 4 + q;
                    pacc = fmaf(wts[srow], sg, pacc);
                }
            }
        }
        __syncthreads();   // XH/shA/wts safe to rewrite next chunk
    }

    // reduce pacc over the 4 row-groups (lanes sharing a column)
    pacc += __shfl_xor(pacc, 16);
    pacc += __shfl_xor(pacc, 32);
    if (rg == 0 && col < 3) red[wv][col] = pacc;
    __syncthreads();
    if (t < 3) out[r * 3 + t] = red[0][t] + red[1][t] + red[2][t] + red[3][t] + Tcs[2];
}

// ---------------- fallback (round-1 kernel) if ws too small ----------------
__global__ __launch_bounds__(256, 2)
void dvgo_render(const float* __restrict__ rays_o, const float* __restrict__ rays_d,
                 const float* __restrict__ dens, const float* __restrict__ k0,
                 const float* __restrict__ w0, const float* __restrict__ b0,
                 const float* __restrict__ w1, const float* __restrict__ b1,
                 const float* __restrict__ w2, const float* __restrict__ b2,
                 float* __restrict__ out)
{
    __shared__ float xs[256 * 40];
    __shared__ float sh[256];
    __shared__ float wts[256];
    __shared__ float h0s[2][128];
    __shared__ float red[2][2][3];
    __shared__ float rgbacc[6];
    __shared__ float ainv_sh;

    const int r = blockIdx.x, tid = threadIdx.x;
    {
        const int s = tid;
        const float ox = rays_o[r*3+0], oy = rays_o[r*3+1], oz = rays_o[r*3+2];
        const float dxr = rays_d[r*3+0], dyr = rays_d[r*3+1], dzr = rays_d[r*3+2];
        const float rn = rsqrtf(dxr*dxr + dyr*dyr + dzr*dzr);
        const float vx = dxr*rn, vy = dyr*rn, vz = dzr*rn;
        const float t = 0.05f + 1.95f * (1.0f/255.0f) * (float)s;
        const float px = ox + vx*t, py = oy + vy*t, pz = oz + vz*t;
        const bool inbox = (px >= -1.f) && (px <= 1.f) && (py >= -1.f) && (py <= 1.f) &&
                           (pz >= -1.f) && (pz <= 1.f);
        const float ix = fminf(fmaxf((px + 1.f) * 79.5f, 0.f), 159.f);
        const float iy = fminf(fmaxf((py + 1.f) * 79.5f, 0.f), 159.f);
        const float iz = fminf(fmaxf((pz + 1.f) * 79.5f, 0.f), 159.f);
        const int x0 = min((int)ix, 158), y0 = min((int)iy, 158), z0 = min((int)iz, 158);
        const float fx = ix - x0, fy = iy - y0, fz = iz - z0;
        const float gx = 1.f - fx, gy = 1.f - fy, gz = 1.f - fz;
        const int DX = 25600, DY = 160;
        const int base = (x0*160 + y0)*160 + z0;
        const float w000=gx*gy*gz, w100=fx*gy*gz, w010=gx*fy*gz, w001=gx*gy*fz;
        const float w110=fx*fy*gz, w101=fx*gy*fz, w011=gx*fy*fz, w111=fx*fy*fz;
        float alpha = 0.f;
        if (inbox) {
            const float d = dens[base]*w000 + dens[base+DX]*w100 + dens[base+DY]*w010 +
                            dens[base+1]*w001 + dens[base+DX+DY]*w110 + dens[base+DX+1]*w101 +
                            dens[base+DY+1]*w011 + dens[base+DX+DY+1]*w111;
            const float e = expf(d + ACT_SHIFT_F);
            const float op = 1.f + e;
            alpha = e / (op + sqrtf(op));
        }
        sh[s] = 1.f - alpha;
        __syncthreads();
        #pragma unroll
        for (int off = 1; off < 256; off <<= 1) {
            const float v = (s >= off) ? sh[s - off] : 1.f;
            __syncthreads();
            sh[s] *= v;
            __syncthreads();
        }
        wts[s] = alpha * ((s == 0) ? 1.f : sh[s-1]);
        if (s == 255) ainv_sh = sh[255];
        if (s < 6) rgbacc[s] = 0.f;
        float* xrow = &xs[s*40];
        if (inbox) {
            #pragma unroll
            for (int c = 0; c < 12; ++c) {
                const float* g = k0 + c*4096000 + base;
                xrow[c] = g[0]*w000 + g[DX]*w100 + g[DY]*w010 + g[1]*w001 +
                          g[DX+DY]*w110 + g[DX+1]*w101 + g[DY+1]*w011 + g[DX+DY+1]*w111;
            }
        } else {
            #pragma unroll
            for (int c = 0; c < 12; ++c) xrow[c] = 0.f;
        }
        xrow[12]=vx; xrow[13]=vy; xrow[14]=vz;
        const float v3[3] = {vx, vy, vz};
        #pragma unroll
        for (int i = 0; i < 3; ++i)
            #pragma unroll
            for (int p = 0; p < 4; ++p) {
                const float a = v3[i] * (float)(1 << p);
                xrow[15 + i*4 + p] = sinf(a);
                xrow[27 + i*4 + p] = cosf(a);
            }
        xrow[39] = 0.f;
    }
    __syncthreads();
    const int j = tid & 127, sb = tid >> 7;
    float w0c[40];
    #pragma unroll
    for (int k = 0; k < 39; ++k) w0c[k] = w0[k*128 + j];
    w0c[39] = 0.f;
    float w1c[128];
    #pragma unroll
    for (int k = 0; k < 128; ++k) w1c[k] = w1[k*128 + j];
    const float b0j = b0[j], b1j = b1[j];
    const float w2r0 = w2[j*3+0], w2r1 = w2[j*3+1], w2r2 = w2[j*3+2];
    const float b20 = b2[0], b21 = b2[1], b22 = b2[2];
    const int lane = tid & 63, halfw = (tid >> 6) & 1;
    for (int it = 0; it < 128; ++it) {
        const int s = it*2 + sb;
        const float4* xrow4 = (const float4*)(&xs[s*40]);
        float acc = b0j;
        #pragma unroll
        for (int q = 0; q < 10; ++q) {
            const float4 v = xrow4[q];
            acc = fmaf(v.x, w0c[q*4+0], acc); acc = fmaf(v.y, w0c[q*4+1], acc);
            acc = fmaf(v.z, w0c[q*4+2], acc); acc = fmaf(v.w, w0c[q*4+3], acc);
        }
        h0s[sb][j] = fmaxf(acc, 0.f);
        __syncthreads();
        float acc1 = b1j;
        const float4* h4 = (const float4*)(&h0s[sb][0]);
        #pragma unroll
        for (int q = 0; q < 32; ++q) {
            const float4 v = h4[q];
            acc1 = fmaf(v.x, w1c[q*4+0], acc1); acc1 = fmaf(v.y, w1c[q*4+1], acc1);
            acc1 = fmaf(v.z, w1c[q*4+2], acc1); acc1 = fmaf(v.w, w1c[q*4+3], acc1);
        }
        const float hv = fmaxf(acc1, 0.f);
        float p0 = hv*w2r0, p1 = hv*w2r1, p2 = hv*w2r2;
        #pragma unroll
        for (int off = 32; off > 0; off >>= 1) {
            p0 += __shfl_down(p0, off); p1 += __shfl_down(p1, off); p2 += __shfl_down(p2, off);
        }
        if (lane == 0) { red[sb][halfw][0]=p0; red[sb][halfw][1]=p1; red[sb][halfw][2]=p2; }
        __syncthreads();
        if (tid == sb*128) {
            const float r0 = red[sb][0][0]+red[sb][1][0]+b20;
            const float r1 = red[sb][0][1]+red[sb][1][1]+b21;
            const float r2 = red[sb][0][2]+red[sb][1][2]+b22;
            const float wgt = wts[s];
            rgbacc[sb*3+0] += wgt / (1.f + expf(-r0));
            rgbacc[sb*3+1] += wgt / (1.f + expf(-r1));
            rgbacc[sb*3+2] += wgt / (1.f + expf(-r2));
        }
    }
    __syncthreads();
    if (tid < 3) out[r*3 + tid] = rgbacc[tid] + rgbacc[3 + tid] + ainv_sh;
}

extern "C" void kernel_launch(void* const* d_in, const int* in_sizes, int n_in,
                              void* d_out, int out_size, void* d_ws, size_t ws_size,
                              hipStream_t stream)
{
    const float* rays_o = (const float*)d_in[0];
    const float* rays_d = (const float*)d_in[1];
    const float* dens   = (const float*)d_in[2];
    const float* k0     = (const float*)d_in[3];
    const float* w0     = (const float*)d_in[4];
    const float* b0     = (const float*)d_in[5];
    const float* w1     = (const float*)d_in[6];
    const float* b1     = (const float*)d_in[7];
    const float* w2     = (const float*)d_in[8];
    const float* b2     = (const float*)d_in[9];
    float* out = (float*)d_out;
    const int N = in_sizes[0] / 3;

    if (ws_size >= WS_NEED) {
        unsigned short* gp  = (unsigned short*)d_ws;
        unsigned short* wpk = (unsigned short*)((char*)d_ws + W0P_OFF);
        repack_all<<<dim3(4011), dim3(256), 0, stream>>>(dens, k0, w0, w1, w2, gp, wpk);
        dvgo_mfma<<<dim3(N), dim3(256), 0, stream>>>(rays_o, rays_d, w0, b0, b1, b2,
                                                     gp, wpk, out);
    } else {
        dvgo_render<<<dim3(N), dim3(256), 0, stream>>>(rays_o, rays_d, dens, k0,
                                                       w0, b0, w1, b1, w2, b2, out);
    }
}

// Round 6
// 456.237 us; speedup vs baseline: 1.0028x; 1.0028x over previous
//
#include <hip/hip_runtime.h>
#include <hip/hip_bf16.h>
#include <math.h>

#define ACT_SHIFT_F (-13.8155095579637744f)
#define GRID_VOX 4096000
#define GP_BYTES  (GRID_VOX * 32)          // fp16 x16 slots per voxel
#define W0P_OFF   GP_BYTES                 // 8 frags  * 1024B
#define W1P_OFF   (W0P_OFF + 8 * 1024)     // 32 frags * 1024B
#define W2P_OFF   (W1P_OFF + 32 * 1024)    // 4 frags  * 1024B
#define WS_NEED   ((size_t)(W2P_OFF + 4 * 1024))

typedef _Float16 f16x8 __attribute__((ext_vector_type(8)));
typedef _Float16 h2    __attribute__((ext_vector_type(2)));
typedef float    f32x4 __attribute__((ext_vector_type(4)));
typedef float    fv4   __attribute__((ext_vector_type(4)));  // clang vector (nontemporal-ok)

// f32 pair -> packed fp16 dword (RNE via v_cvt_f16_f32)
__device__ __forceinline__ unsigned int pkh2(float a, float b) {
    h2 v; v.x = (_Float16)a; v.y = (_Float16)b;
    return __builtin_bit_cast(unsigned int, v);
}
__device__ __forceinline__ unsigned short f2h(float x) {
    _Float16 h = (_Float16)x; return __builtin_bit_cast(unsigned short, h);
}

// ---------------- repack (fused): grid -> interleaved fp16 [vox][16]; W -> B-frags ----
// Slot order: 0..11 = k0 channels, 12..14 = 0, 15 = density (so phase A's X-row
// stores are dword-aligned and density rides the pad slot).
__global__ void repack_all(const float* __restrict__ dens, const float* __restrict__ k0,
                           const float* __restrict__ w0, const float* __restrict__ w1,
                           const float* __restrict__ w2,
                           unsigned short* __restrict__ gp, unsigned short* __restrict__ wp)
{
    const int b = blockIdx.x;
    if (b < 4000) {
        const int v4 = b * 1024 + threadIdx.x * 4;       // 4 consecutive voxels
        const fv4 d4 = __builtin_nontemporal_load((const fv4*)(dens + v4));
        fv4 c4[12];
        #pragma unroll
        for (int c = 0; c < 12; ++c)
            c4[c] = __builtin_nontemporal_load((const fv4*)(k0 + (size_t)c * GRID_VOX + v4));
        uint4* dst = (uint4*)(gp + (size_t)v4 * 16);
        #pragma unroll
        for (int j = 0; j < 4; ++j) {
            const float* cj = &((const float*)c4)[j];     // c4[c] component j at cj[4*c]
            uint4 q0, q1;
            q0.x = pkh2(cj[4*0],  cj[4*1]);
            q0.y = pkh2(cj[4*2],  cj[4*3]);
            q0.z = pkh2(cj[4*4],  cj[4*5]);
            q0.w = pkh2(cj[4*6],  cj[4*7]);
            q1.x = pkh2(cj[4*8],  cj[4*9]);
            q1.y = pkh2(cj[4*10], cj[4*11]);
            q1.z = 0u;                        // slots 12,13
            q1.w = pkh2(0.f, d4[j]);          // slot 14 = 0, slot 15 = density
            dst[j*2 + 0] = q0;
            dst[j*2 + 1] = q1;
        }
        return;
    }
    // ---- weight repack: B-frag (16x16x32): lane l holds B[k=(l>>4)*8+j][n=l&15] ----
    const int t = (b - 4000) * 256 + threadIdx.x;
    if (t >= 44 * 64) return;
    const int f = t >> 6, l = t & 63;
    const int n16 = l & 15, kg = l >> 4;
    unsigned short v[8];
    if (f < 8) {                       // W0: ntile=f, K=32 (feature rows 0..11 real)
        const int n = f * 16 + n16;
        #pragma unroll
        for (int j = 0; j < 8; ++j) {
            const int k = kg * 8 + j;
            v[j] = (k < 12) ? f2h(w0[k * 128 + n]) : (unsigned short)0;
        }
    } else if (f < 40) {               // W1: frag (nt, ks)
        const int ff = f - 8, nt = ff >> 2, ks = ff & 3;
        const int n = nt * 16 + n16;
        #pragma unroll
        for (int j = 0; j < 8; ++j) {
            const int k = ks * 32 + kg * 8 + j;
            v[j] = f2h(w1[k * 128 + n]);
        }
    } else {                           // W2: N=16 (cols 0..2 real), frag ks
        const int ks = f - 40;
        #pragma unroll
        for (int j = 0; j < 8; ++j) {
            const int k = ks * 32 + kg * 8 + j;
            v[j] = (n16 < 3) ? f2h(w2[k * 3 + n16]) : (unsigned short)0;
        }
    }
    uint4 q;
    q.x = v[0] | (v[1] << 16); q.y = v[2] | (v[3] << 16);
    q.z = v[4] | (v[5] << 16); q.w = v[6] | (v[7] << 16);
    *(uint4*)(wp + f * 512 + l * 8) = q;
}

// voxel-corner offsets (in voxel units; *2 applied at use site for uint4 pairs)
#define OFF_C0 0
#define OFF_C1 1
#define OFF_C2 160
#define OFF_C3 161
#define OFF_C4 25600
#define OFF_C5 25601
#define OFF_C6 25760
#define OFF_C7 25761

// issue the 8 corner loads for chunk CK into named regs pq0..pq7
#define ISSUE_GATHER(CK) do {                                                        \
    const int s_ = (CK) * 128 + sl;                                                  \
    const float tp_ = 0.05f + (1.95f / 255.f) * (float)s_;                           \
    const float px_ = ox + vx*tp_, py_ = oy + vy*tp_, pz_ = oz + vz*tp_;             \
    inbox_p = (px_ >= -1.f) & (px_ <= 1.f) & (py_ >= -1.f) & (py_ <= 1.f) &          \
              (pz_ >= -1.f) & (pz_ <= 1.f);                                          \
    if (inbox_p) {                                                                   \
        const float ix_ = fminf(fmaxf((px_ + 1.f) * 79.5f, 0.f), 159.f);             \
        const float iy_ = fminf(fmaxf((py_ + 1.f) * 79.5f, 0.f), 159.f);             \
        const float iz_ = fminf(fmaxf((pz_ + 1.f) * 79.5f, 0.f), 159.f);             \
        const int x0_ = min((int)ix_, 158), y0_ = min((int)iy_, 158),                \
                  z0_ = min((int)iz_, 158);                                          \
        const size_t b_ = (size_t)((x0_ * 160 + y0_) * 160 + z0_) * 2 + hf;          \
        pq0 = gq[b_ + OFF_C0*2]; pq1 = gq[b_ + OFF_C1*2];                            \
        pq2 = gq[b_ + OFF_C2*2]; pq3 = gq[b_ + OFF_C3*2];                            \
        pq4 = gq[b_ + OFF_C4*2]; pq5 = gq[b_ + OFF_C5*2];                            \
        pq6 = gq[b_ + OFF_C6*2]; pq7 = gq[b_ + OFF_C7*2];                            \
    }                                                                                \
} while (0)

// ---------------- main render: one block per ray ----------------
// Changes vs prior round (anti-spill levers; r5 showed the allocator targets
// 6 waves/EU (84 VGPR) and spills ~130-reg demand at 80 MB/dispatch):
//  - amdgpu_waves_per_eu(3,4) + flat_work_group_size(256,256), NO launch_bounds:
//    max=4 matches the LDS-imposed occupancy ceiling (37.4KB -> 4 blocks/CU =
//    4 waves/EU), so the allocator's register target becomes 512/4 = 128 >= our
//    demand; min=3 keeps the hard budget at 170. (r2's failed attempt combined
//    waves_per_eu with __launch_bounds__, which overrides these attributes.)
//  - W2 fragment load moved AFTER L1 (its L2 latency overlaps the pre-L2 barrier
//    instead of adding 16 live regs through the L1 pressure peak).
__global__ __attribute__((amdgpu_flat_work_group_size(256, 256), amdgpu_waves_per_eu(3, 4)))
void dvgo_mfma(const float* __restrict__ rays_o, const float* __restrict__ rays_d,
               const float* __restrict__ w0, const float* __restrict__ b0,
               const float* __restrict__ b1, const float* __restrict__ b2,
               const unsigned short* __restrict__ gp,   // packed grid
               const unsigned short* __restrict__ wpk,  // packed weights
               float* __restrict__ out)
{
    __shared__ unsigned short XH[128 * 136]; // union: Xs[128][40] / Hs[128][136]
    __shared__ float shA[128];                // per-chunk (1-alpha)
    __shared__ float wts[128];                // alpha, then final weights
    __shared__ float b0eff[128];
    __shared__ float b1s[128];
    __shared__ float vemb[28];
    __shared__ float red[4][3];
    __shared__ float b2s[3];
    __shared__ float Tcs[3];                  // carry: T before chunk ck; Tcs[2]=ainv
    __shared__ float spart;                   // wave0 scan total

    const int r = blockIdx.x, t = threadIdx.x;
    const int l = t & 63, wv = t >> 6;
    const int col = l & 15, rg = l >> 4;
    const int sl = t >> 1, hf = t & 1;

    const float ox = rays_o[r*3+0], oy = rays_o[r*3+1], oz = rays_o[r*3+2];
    const float dxr = rays_d[r*3+0], dyr = rays_d[r*3+1], dzr = rays_d[r*3+2];
    const float rn = rsqrtf(dxr*dxr + dyr*dyr + dzr*dzr);
    const float vx = dxr*rn, vy = dyr*rn, vz = dzr*rn;

    const uint4* gq = (const uint4*)gp;
    _Float16* XHh = (_Float16*)XH;

    // ---- prefetched gather state (named regs, held across the MLP) ----
    uint4 pq0, pq1, pq2, pq3, pq4, pq5, pq6, pq7;
    bool inbox_p = false;

    ISSUE_GATHER(0);   // chunk-0 gathers fly during the setup phase below

    // ---- phase 0: vemb, biases ----
    if (t < 27) {
        float val;
        if (t < 3) val = (t == 0) ? vx : ((t == 1) ? vy : vz);
        else {
            int q = t - 3;
            const bool is_sin = q < 12;
            if (!is_sin) q -= 12;
            const int i = q >> 2, p = q & 3;
            const float a = ((i == 0) ? vx : ((i == 1) ? vy : vz)) * (float)(1 << p);
            val = is_sin ? sinf(a) : cosf(a);
        }
        vemb[t] = val;
    }
    if (t < 3)   b2s[t] = b2[t];
    if (t < 128) b1s[t] = b1[t];
    if (t == 0)  Tcs[0] = 1.f;
    __syncthreads();

    if (t < 128) {                       // fold view embedding into layer-0 bias
        float a = b0[t];
        #pragma unroll
        for (int k = 0; k < 27; ++k) a = fmaf(vemb[k], w0[(12 + k) * 128 + t], a);
        b0eff[t] = a;
    }

    const unsigned short* w0p = wpk;
    const unsigned short* w1p = wpk + 8 * 512;
    const unsigned short* w2p = wpk + 40 * 512;

    float pacc = 0.f;   // per-lane weighted-rgb accumulator (cols 0..2 meaningful)

    #pragma unroll 1
    for (int ck = 0; ck < 2; ++ck) {
        // ---- phase A: consume prefetched gathers -> X rows, alpha ----
        {
            unsigned int* xd = (unsigned int*)&XH[sl * 40];
            if (inbox_p) {
                // recompute trilerp fractions (cheap; avoids holding w8 across MLP)
                const int s = ck * 128 + sl;
                const float tp = 0.05f + (1.95f / 255.f) * (float)s;
                const float px = ox + vx*tp, py = oy + vy*tp, pz = oz + vz*tp;
                const float ix = fminf(fmaxf((px + 1.f) * 79.5f, 0.f), 159.f);
                const float iy = fminf(fmaxf((py + 1.f) * 79.5f, 0.f), 159.f);
                const float iz = fminf(fmaxf((pz + 1.f) * 79.5f, 0.f), 159.f);
                const int x0 = min((int)ix, 158), y0 = min((int)iy, 158), z0 = min((int)iz, 158);
                const float fx = ix - x0, fy = iy - y0, fz = iz - z0;
                const float gx = 1.f - fx, gy = 1.f - fy, gz = 1.f - fz;
                float w8[8];
                w8[0]=gx*gy*gz; w8[1]=gx*gy*fz; w8[2]=gx*fy*gz; w8[3]=gx*fy*fz;
                w8[4]=fx*gy*gz; w8[5]=fx*gy*fz; w8[6]=fx*fy*gz; w8[7]=fx*fy*fz;
                h2 ah0 = {0, 0}, ah1 = {0, 0}, ah2 = {0, 0}, ah3 = {0, 0};
                #define CONSUME(Q, WI) {                                             \
                    h2 wc2; wc2.x = (_Float16)w8[WI]; wc2.y = wc2.x;                 \
                    ah0 += __builtin_bit_cast(h2, (Q).x) * wc2;                      \
                    ah1 += __builtin_bit_cast(h2, (Q).y) * wc2;                      \
                    ah2 += __builtin_bit_cast(h2, (Q).z) * wc2;                      \
                    ah3 += __builtin_bit_cast(h2, (Q).w) * wc2;                      \
                }
                CONSUME(pq0, 0); CONSUME(pq1, 1); CONSUME(pq2, 2); CONSUME(pq3, 3);
                CONSUME(pq4, 4); CONSUME(pq5, 5); CONSUME(pq6, 6); CONSUME(pq7, 7);
                #undef CONSUME
                if (hf == 0) {   // slots 0..7 = feat0..7 -> X cols 0..7
                    xd[0] = __builtin_bit_cast(unsigned int, ah0);
                    xd[1] = __builtin_bit_cast(unsigned int, ah1);
                    xd[2] = __builtin_bit_cast(unsigned int, ah2);
                    xd[3] = __builtin_bit_cast(unsigned int, ah3);
                } else {         // slots 8..15 = feat8..11, 0,0,0, dens
                    xd[4] = __builtin_bit_cast(unsigned int, ah0);
                    xd[5] = __builtin_bit_cast(unsigned int, ah1);
                    xd[6] = 0u;                    // cols 12,13
                    xd[7] = 0u;                    // cols 14,15 (NOT dens)
                    const float dv = (float)ah3.y; // slot 15 = density trilerp
                    const float e = expf(dv + ACT_SHIFT_F);
                    const float op = 1.f + e;
                    const float alpha = e / (op + sqrtf(op));   // 1-(1+e)^(-1/2)
                    wts[sl] = alpha;
                    shA[sl] = 1.f - alpha;
                }
            } else {
                if (hf == 0) {
                    xd[0]=0u; xd[1]=0u; xd[2]=0u; xd[3]=0u;
                } else {
                    xd[4]=0u; xd[5]=0u; xd[6]=0u; xd[7]=0u;
                    wts[sl] = 0.f;
                    shA[sl] = 1.f;
                }
            }
            // zero pad cols 16..31 (K=32 tail) — every chunk (union leaves Hs bytes)
            if (hf == 0) { xd[8]=0u;  xd[9]=0u;  xd[10]=0u; xd[11]=0u; }
            else         { xd[12]=0u; xd[13]=0u; xd[14]=0u; xd[15]=0u; }
            if (ck == 0) ISSUE_GATHER(1);   // chunk-1 loads hide under scan + MLP
        }
        __syncthreads();   // Xs/shA/alpha complete

        const int row0 = wv * 32;   // this wave owns sample-rows [row0, row0+32)

        // ---- A0 fragment preload: MUST precede the next barrier (Xs dies here;
        //      Hs writes below would otherwise clobber other waves' unread Xs rows)
        f16x8 A0[2];
        #pragma unroll
        for (int mt = 0; mt < 2; ++mt)
            A0[mt] = *(const f16x8*)(&XH[(row0 + mt * 16 + col) * 40 + rg * 8]);

        // ---- transmittance scan (threads 0..127 = waves 0,1), carry Tcs[ck] ----
        float v = 1.f;
        if (t < 128) {
            v = shA[t];
            #pragma unroll
            for (int off = 1; off < 64; off <<= 1) {
                const float u = __shfl_up(v, off);
                if (l >= off) v *= u;
            }
            if (wv == 0 && l == 63) spart = v;
        }
        __syncthreads();   // spart visible; also: all waves' A0 loads complete
        if (t < 128) {     // scan tail (waves 0-1); waves 2-3 fall through to L0
            float excl = __shfl_up(v, 1);
            if (l == 0) excl = 1.f;
            float E = Tcs[ck];
            const float sp = spart;
            if (wv == 1) E *= sp;
            const float w = wts[t] * E * excl;
            wts[t] = w;
            if (t == 127) Tcs[ck + 1] = Tcs[ck] * sp * v;
        }
        // (no barrier here: wts not read until L2 epilogue; Hs rows wave-private)

        // ---- layer 0: H0 = relu(X*W0 + b0eff), K=32; even/odd B prefetch ----
        {
            #define L0_STEP(B, NT) {                                                  \
                const float bias = b0eff[(NT) * 16 + col];                            \
                _Pragma("unroll")                                                     \
                for (int mt = 0; mt < 2; ++mt) {                                      \
                    f32x4 acc = {bias, bias, bias, bias};                             \
                    acc = __builtin_amdgcn_mfma_f32_16x16x32_f16(A0[mt], B, acc, 0, 0, 0); \
                    _Pragma("unroll")                                                 \
                    for (int q = 0; q < 4; ++q) {                                     \
                        const float vv = fmaxf(acc[q], 0.f);                          \
                        const int row = row0 + mt * 16 + rg * 4 + q;                  \
                        XHh[row * 136 + (NT) * 16 + col] = (_Float16)vv;              \
                    }                                                                 \
                }                                                                     \
            }
            f16x8 Ba = *(const f16x8*)(w0p + l * 8);
            #pragma unroll 1
            for (int nt = 0; nt < 8; nt += 2) {
                const f16x8 Bb = *(const f16x8*)(w0p + (nt + 1) * 512 + l * 8);
                L0_STEP(Ba, nt);
                if (nt < 6) Ba = *(const f16x8*)(w0p + (nt + 2) * 512 + l * 8);
                L0_STEP(Bb, nt + 1);
            }
            #undef L0_STEP
        }

        // ---- layer 1: H1 = relu(H0*W1 + b1), K=128, in-place, even/odd prefetch ----
        {
            f16x8 A1[2][4];
            #pragma unroll
            for (int mt = 0; mt < 2; ++mt)
                #pragma unroll
                for (int ks = 0; ks < 4; ++ks)
                    A1[mt][ks] = *(const f16x8*)(&XH[(row0 + mt * 16 + col) * 136 + ks * 32 + rg * 8]);
            #define L1_STEP(BK, NT) {                                                 \
                const float bias = b1s[(NT) * 16 + col];                              \
                _Pragma("unroll")                                                     \
                for (int mt = 0; mt < 2; ++mt) {                                      \
                    f32x4 acc = {bias, bias, bias, bias};                             \
                    _Pragma("unroll")                                                 \
                    for (int ks = 0; ks < 4; ++ks)                                    \
                        acc = __builtin_amdgcn_mfma_f32_16x16x32_f16(A1[mt][ks], BK[ks], acc, 0, 0, 0); \
                    _Pragma("unroll")                                                 \
                    for (int q = 0; q < 4; ++q) {                                     \
                        const float vv = fmaxf(acc[q], 0.f);                          \
                        const int row = row0 + mt * 16 + rg * 4 + q;                  \
                        XHh[row * 136 + (NT) * 16 + col] = (_Float16)vv;              \
                    }                                                                 \
                }                                                                     \
            }
            f16x8 BkA[4], BkB[4];
            #pragma unroll
            for (int ks = 0; ks < 4; ++ks)
                BkA[ks] = *(const f16x8*)(w1p + ks * 512 + l * 8);
            #pragma unroll 1
            for (int nt = 0; nt < 8; nt += 2) {
                #pragma unroll
                for (int ks = 0; ks < 4; ++ks)
                    BkB[ks] = *(const f16x8*)(w1p + ((nt + 1) * 4 + ks) * 512 + l * 8);
                L1_STEP(BkA, nt);
                if (nt < 6) {
                    #pragma unroll
                    for (int ks = 0; ks < 4; ++ks)
                        BkA[ks] = *(const f16x8*)(w1p + ((nt + 2) * 4 + ks) * 512 + l * 8);
                }
                L1_STEP(BkB, nt + 1);
            }
            #undef L1_STEP
        }

        // ---- W2 fragments: load AFTER L1 (latency overlaps the barrier below) ----
        f16x8 W2k[4];
        #pragma unroll
        for (int ks = 0; ks < 4; ++ks)
            W2k[ks] = *(const f16x8*)(w2p + ks * 512 + l * 8);

        __syncthreads();   // wts (scan tail) visible to all waves; Hs wave-private

        // ---- layer 2 + epilogue: rgb = sigmoid(H1*W2 + b2); pacc += wts*rgb ----
        {
            const float bias2 = (col < 3) ? b2s[col] : 0.f;
            #pragma unroll
            for (int mt = 0; mt < 2; ++mt) {
                f16x8 A2[4];
                #pragma unroll
                for (int ks = 0; ks < 4; ++ks)
                    A2[ks] = *(const f16x8*)(&XH[(row0 + mt * 16 + col) * 136 + ks * 32 + rg * 8]);
                f32x4 acc = {bias2, bias2, bias2, bias2};
                #pragma unroll
                for (int ks = 0; ks < 4; ++ks)
                    acc = __builtin_amdgcn_mfma_f32_16x16x32_f16(A2[ks], W2k[ks], acc, 0, 0, 0);
                #pragma unroll
                for (int q = 0; q < 4; ++q) {
                    const float sg = 1.f / (1.f + expf(-acc[q]));
                    const int srow = row0 + mt * 16 + rg * 4 + q;
                    pacc = fmaf(wts[srow], sg, pacc);
                }
            }
        }
        __syncthreads();   // XH/shA/wts safe to rewrite next chunk
    }

    // reduce pacc over the 4 row-groups (lanes sharing a column)
    pacc += __shfl_xor(pacc, 16);
    pacc += __shfl_xor(pacc, 32);
    if (rg == 0 && col < 3) red[wv][col] = pacc;
    __syncthreads();
    if (t < 3) out[r * 3 + t] = red[0][t] + red[1][t] + red[2][t] + red[3][t] + Tcs[2];
}

// ---------------- fallback (round-1 kernel) if ws too small ----------------
__global__ __launch_bounds__(256, 2)
void dvgo_render(const float* __restrict__ rays_o, const float* __restrict__ rays_d,
                 const float* __restrict__ dens, const float* __restrict__ k0,
                 const float* __restrict__ w0, const float* __restrict__ b0,
                 const float* __restrict__ w1, const float* __restrict__ b1,
                 const float* __restrict__ w2, const float* __restrict__ b2,
                 float* __restrict__ out)
{
    __shared__ float xs[256 * 40];
    __shared__ float sh[256];
    __shared__ float wts[256];
    __shared__ float h0s[2][128];
    __shared__ float red[2][2][3];
    __shared__ float rgbacc[6];
    __shared__ float ainv_sh;

    const int r = blockIdx.x, tid = threadIdx.x;
    {
        const int s = tid;
        const float ox = rays_o[r*3+0], oy = rays_o[r*3+1], oz = rays_o[r*3+2];
        const float dxr = rays_d[r*3+0], dyr = rays_d[r*3+1], dzr = rays_d[r*3+2];
        const float rn = rsqrtf(dxr*dxr + dyr*dyr + dzr*dzr);
        const float vx = dxr*rn, vy = dyr*rn, vz = dzr*rn;
        const float t = 0.05f + 1.95f * (1.0f/255.0f) * (float)s;
        const float px = ox + vx*t, py = oy + vy*t, pz = oz + vz*t;
        const bool inbox = (px >= -1.f) && (px <= 1.f) && (py >= -1.f) && (py <= 1.f) &&
                           (pz >= -1.f) && (pz <= 1.f);
        const float ix = fminf(fmaxf((px + 1.f) * 79.5f, 0.f), 159.f);
        const float iy = fminf(fmaxf((py + 1.f) * 79.5f, 0.f), 159.f);
        const float iz = fminf(fmaxf((pz + 1.f) * 79.5f, 0.f), 159.f);
        const int x0 = min((int)ix, 158), y0 = min((int)iy, 158), z0 = min((int)iz, 158);
        const float fx = ix - x0, fy = iy - y0, fz = iz - z0;
        const float gx = 1.f - fx, gy = 1.f - fy, gz = 1.f - fz;
        const int DX = 25600, DY = 160;
        const int base = (x0*160 + y0)*160 + z0;
        const float w000=gx*gy*gz, w100=fx*gy*gz, w010=gx*fy*gz, w001=gx*gy*fz;
        const float w110=fx*fy*gz, w101=fx*gy*fz, w011=gx*fy*fz, w111=fx*fy*fz;
        float alpha = 0.f;
        if (inbox) {
            const float d = dens[base]*w000 + dens[base+DX]*w100 + dens[base+DY]*w010 +
                            dens[base+1]*w001 + dens[base+DX+DY]*w110 + dens[base+DX+1]*w101 +
                            dens[base+DY+1]*w011 + dens[base+DX+DY+1]*w111;
            const float e = expf(d + ACT_SHIFT_F);
            const float op = 1.f + e;
            alpha = e / (op + sqrtf(op));
        }
        sh[s] = 1.f - alpha;
        __syncthreads();
        #pragma unroll
        for (int off = 1; off < 256; off <<= 1) {
            const float v = (s >= off) ? sh[s - off] : 1.f;
            __syncthreads();
            sh[s] *= v;
            __syncthreads();
        }
        wts[s] = alpha * ((s == 0) ? 1.f : sh[s-1]);
        if (s == 255) ainv_sh = sh[255];
        if (s < 6) rgbacc[s] = 0.f;
        float* xrow = &xs[s*40];
        if (inbox) {
            #pragma unroll
            for (int c = 0; c < 12; ++c) {
                const float* g = k0 + c*4096000 + base;
                xrow[c] = g[0]*w000 + g[DX]*w100 + g[DY]*w010 + g[1]*w001 +
                          g[DX+DY]*w110 + g[DX+1]*w101 + g[DY+1]*w011 + g[DX+DY+1]*w111;
            }
        } else {
            #pragma unroll
            for (int c = 0; c < 12; ++c) xrow[c] = 0.f;
        }
        xrow[12]=vx; xrow[13]=vy; xrow[14]=vz;
        const float v3[3] = {vx, vy, vz};
        #pragma unroll
        for (int i = 0; i < 3; ++i)
            #pragma unroll
            for (int p = 0; p < 4; ++p) {
                const float a = v3[i] * (float)(1 << p);
                xrow[15 + i*4 + p] = sinf(a);
                xrow[27 + i*4 + p] = cosf(a);
            }
        xrow[39] = 0.f;
    }
    __syncthreads();
    const int j = tid & 127, sb = tid >> 7;
    float w0c[40];
    #pragma unroll
    for (int k = 0; k < 39; ++k) w0c[k] = w0[k*128 + j];
    w0c[39] = 0.f;
    float w1c[128];
    #pragma unroll
    for (int k = 0; k < 128; ++k) w1c[k] = w1[k*128 + j];
    const float b0j = b0[j], b1j = b1[j];
    const float w2r0 = w2[j*3+0], w2r1 = w2[j*3+1], w2r2 = w2[j*3+2];
    const float b20 = b2[0], b21 = b2[1], b22 = b2[2];
    const int lane = tid & 63, halfw = (tid >> 6) & 1;
    for (int it = 0; it < 128; ++it) {
        const int s = it*2 + sb;
        const float4* xrow4 = (const float4*)(&xs[s*40]);
        float acc = b0j;
        #pragma unroll
        for (int q = 0; q < 10; ++q) {
            const float4 v = xrow4[q];
            acc = fmaf(v.x, w0c[q*4+0], acc); acc = fmaf(v.y, w0c[q*4+1], acc);
            acc = fmaf(v.z, w0c[q*4+2], acc); acc = fmaf(v.w, w0c[q*4+3], acc);
        }
        h0s[sb][j] = fmaxf(acc, 0.f);
        __syncthreads();
        float acc1 = b1j;
        const float4* h4 = (const float4*)(&h0s[sb][0]);
        #pragma unroll
        for (int q = 0; q < 32; ++q) {
            const float4 v = h4[q];
            acc1 = fmaf(v.x, w1c[q*4+0], acc1); acc1 = fmaf(v.y, w1c[q*4+1], acc1);
            acc1 = fmaf(v.z, w1c[q*4+2], acc1); acc1 = fmaf(v.w, w1c[q*4+3], acc1);
        }
        const float hv = fmaxf(acc1, 0.f);
        float p0 = hv*w2r0, p1 = hv*w2r1, p2 = hv*w2r2;
        #pragma unroll
        for (int off = 32; off > 0; off >>= 1) {
            p0 += __shfl_down(p0, off); p1 += __shfl_down(p1, off); p2 += __shfl_down(p2, off);
        }
        if (lane == 0) { red[sb][halfw][0]=p0; red[sb][halfw][1]=p1; red[sb][halfw][2]=p2; }
        __syncthreads();
        if (tid == sb*128) {
            const float r0 = red[sb][0][0]+red[sb][1][0]+b20;
            const float r1 = red[sb][0][1]+red[sb][1][1]+b21;
            const float r2 = red[sb][0][2]+red[sb][1][2]+b22;
            const float wgt = wts[s];
            rgbacc[sb*3+0] += wgt / (1.f + expf(-r0));
            rgbacc[sb*3+1] += wgt / (1.f + expf(-r1));
            rgbacc[sb*3+2] += wgt / (1.f + expf(-r2));
        }
    }
    __syncthreads();
    if (tid < 3) out[r*3 + tid] = rgbacc[tid] + rgbacc[3 + tid] + ainv_sh;
}

extern "C" void kernel_launch(void* const* d_in, const int* in_sizes, int n_in,
                              void* d_out, int out_size, void* d_ws, size_t ws_size,
                              hipStream_t stream)
{
    const float* rays_o = (const float*)d_in[0];
    const float* rays_d = (const float*)d_in[1];
    const float* dens   = (const float*)d_in[2];
    const float* k0     = (const float*)d_in[3];
    const float* w0     = (const float*)d_in[4];
    const float* b0     = (const float*)d_in[5];
    const float* w1     = (const float*)d_in[6];
    const float* b1     = (const float*)d_in[7];
    const float* w2     = (const float*)d_in[8];
    const float* b2     = (const float*)d_in[9];
    float* out = (float*)d_out;
    const int N = in_sizes[0] / 3;

    if (ws_size >= WS_NEED) {
        unsigned short* gp  = (unsigned short*)d_ws;
        unsigned short* wpk = (unsigned short*)((char*)d_ws + W0P_OFF);
        repack_all<<<dim3(4011), dim3(256), 0, stream>>>(dens, k0, w0, w1, w2, gp, wpk);
        dvgo_mfma<<<dim3(N), dim3(256), 0, stream>>>(rays_o, rays_d, w0, b0, b1, b2,
                                                     gp, wpk, out);
    } else {
        dvgo_render<<<dim3(N), dim3(256), 0, stream>>>(rays_o, rays_d, dens, k0,
                                                       w0, b0, w1, b1, w2, b2, out);
    }
}

// Round 7
// 455.544 us; speedup vs baseline: 1.0043x; 1.0015x over previous
//
#include <hip/hip_runtime.h>
#include <hip/hip_bf16.h>
#include <math.h>

#define ACT_SHIFT_F (-13.8155095579637744f)
#define GRID_VOX 4096000
#define GP_BYTES  (GRID_VOX * 32)          // fp16 x16 slots per voxel
#define W0P_OFF   GP_BYTES                 // 8 frags  * 1024B
#define W1P_OFF   (W0P_OFF + 8 * 1024)     // 32 frags * 1024B
#define W2P_OFF   (W1P_OFF + 32 * 1024)    // 4 frags  * 1024B
#define WS_NEED   ((size_t)(W2P_OFF + 4 * 1024))

typedef _Float16 f16x8 __attribute__((ext_vector_type(8)));
typedef _Float16 h2    __attribute__((ext_vector_type(2)));
typedef float    f32x4 __attribute__((ext_vector_type(4)));
typedef float    fv4   __attribute__((ext_vector_type(4)));  // clang vector (nontemporal-ok)

// f32 pair -> packed fp16 dword (RNE via v_cvt_f16_f32)
__device__ __forceinline__ unsigned int pkh2(float a, float b) {
    h2 v; v.x = (_Float16)a; v.y = (_Float16)b;
    return __builtin_bit_cast(unsigned int, v);
}
__device__ __forceinline__ unsigned short f2h(float x) {
    _Float16 h = (_Float16)x; return __builtin_bit_cast(unsigned short, h);
}

// ---------------- repack (fused): grid -> interleaved fp16 [vox][16]; W -> B-frags ----
// Slot order: 0..11 = k0 channels, 12..14 = 0, 15 = density (so phase A's X-row
// stores are dword-aligned and density rides the pad slot).
__global__ void repack_all(const float* __restrict__ dens, const float* __restrict__ k0,
                           const float* __restrict__ w0, const float* __restrict__ w1,
                           const float* __restrict__ w2,
                           unsigned short* __restrict__ gp, unsigned short* __restrict__ wp)
{
    const int b = blockIdx.x;
    if (b < 4000) {
        const int v4 = b * 1024 + threadIdx.x * 4;       // 4 consecutive voxels
        const fv4 d4 = __builtin_nontemporal_load((const fv4*)(dens + v4));
        fv4 c4[12];
        #pragma unroll
        for (int c = 0; c < 12; ++c)
            c4[c] = __builtin_nontemporal_load((const fv4*)(k0 + (size_t)c * GRID_VOX + v4));
        uint4* dst = (uint4*)(gp + (size_t)v4 * 16);
        #pragma unroll
        for (int j = 0; j < 4; ++j) {
            const float* cj = &((const float*)c4)[j];     // c4[c] component j at cj[4*c]
            uint4 q0, q1;
            q0.x = pkh2(cj[4*0],  cj[4*1]);
            q0.y = pkh2(cj[4*2],  cj[4*3]);
            q0.z = pkh2(cj[4*4],  cj[4*5]);
            q0.w = pkh2(cj[4*6],  cj[4*7]);
            q1.x = pkh2(cj[4*8],  cj[4*9]);
            q1.y = pkh2(cj[4*10], cj[4*11]);
            q1.z = 0u;                        // slots 12,13
            q1.w = pkh2(0.f, d4[j]);          // slot 14 = 0, slot 15 = density
            dst[j*2 + 0] = q0;
            dst[j*2 + 1] = q1;
        }
        return;
    }
    // ---- weight repack: B-frag (16x16x32): lane l holds B[k=(l>>4)*8+j][n=l&15] ----
    const int t = (b - 4000) * 256 + threadIdx.x;
    if (t >= 44 * 64) return;
    const int f = t >> 6, l = t & 63;
    const int n16 = l & 15, kg = l >> 4;
    unsigned short v[8];
    if (f < 8) {                       // W0: ntile=f, K=32 (feature rows 0..11 real)
        const int n = f * 16 + n16;
        #pragma unroll
        for (int j = 0; j < 8; ++j) {
            const int k = kg * 8 + j;
            v[j] = (k < 12) ? f2h(w0[k * 128 + n]) : (unsigned short)0;
        }
    } else if (f < 40) {               // W1: frag (nt, ks)
        const int ff = f - 8, nt = ff >> 2, ks = ff & 3;
        const int n = nt * 16 + n16;
        #pragma unroll
        for (int j = 0; j < 8; ++j) {
            const int k = ks * 32 + kg * 8 + j;
            v[j] = f2h(w1[k * 128 + n]);
        }
    } else {                           // W2: N=16 (cols 0..2 real), frag ks
        const int ks = f - 40;
        #pragma unroll
        for (int j = 0; j < 8; ++j) {
            const int k = ks * 32 + kg * 8 + j;
            v[j] = (n16 < 3) ? f2h(w2[k * 3 + n16]) : (unsigned short)0;
        }
    }
    uint4 q;
    q.x = v[0] | (v[1] << 16); q.y = v[2] | (v[3] << 16);
    q.z = v[4] | (v[5] << 16); q.w = v[6] | (v[7] << 16);
    *(uint4*)(wp + f * 512 + l * 8) = q;
}

// voxel-corner offsets (in voxel units; *2 applied at use site for uint4 pairs)
#define OFF_C0 0
#define OFF_C1 1
#define OFF_C2 160
#define OFF_C3 161
#define OFF_C4 25600
#define OFF_C5 25601
#define OFF_C6 25760
#define OFF_C7 25761

// issue the 8 corner loads for chunk CK into named regs pq0..pq7
#define ISSUE_GATHER(CK) do {                                                        \
    const int s_ = (CK) * 128 + sl;                                                  \
    const float tp_ = 0.05f + (1.95f / 255.f) * (float)s_;                           \
    const float px_ = ox + vx*tp_, py_ = oy + vy*tp_, pz_ = oz + vz*tp_;             \
    inbox_p = (px_ >= -1.f) & (px_ <= 1.f) & (py_ >= -1.f) & (py_ <= 1.f) &          \
              (pz_ >= -1.f) & (pz_ <= 1.f);                                          \
    if (inbox_p) {                                                                   \
        const float ix_ = fminf(fmaxf((px_ + 1.f) * 79.5f, 0.f), 159.f);             \
        const float iy_ = fminf(fmaxf((py_ + 1.f) * 79.5f, 0.f), 159.f);             \
        const float iz_ = fminf(fmaxf((pz_ + 1.f) * 79.5f, 0.f), 159.f);             \
        const int x0_ = min((int)ix_, 158), y0_ = min((int)iy_, 158),                \
                  z0_ = min((int)iz_, 158);                                          \
        const size_t b_ = (size_t)((x0_ * 160 + y0_) * 160 + z0_) * 2 + hf;          \
        pq0 = gq[b_ + OFF_C0*2]; pq1 = gq[b_ + OFF_C1*2];                            \
        pq2 = gq[b_ + OFF_C2*2]; pq3 = gq[b_ + OFF_C3*2];                            \
        pq4 = gq[b_ + OFF_C4*2]; pq5 = gq[b_ + OFF_C5*2];                            \
        pq6 = gq[b_ + OFF_C6*2]; pq7 = gq[b_ + OFF_C7*2];                            \
    }                                                                                \
} while (0)

// ---------------- main render: one block per ray ----------------
// Changes vs prior round (demand-cut lever; r6 proved attributes can't move the
// allocator off 84 VGPRs, so demand must fit under 84):
//  - next-chunk gather (pq0..7, 32 regs) issued AFTER L1 instead of in phase A.
//    Its latency hides under W2k load + barrier + L2 + epilogue + next phase-A
//    address math. L1 peak: A1 32 + Bk 32 + misc ~16 <= 84. L2 peak: A2 16 +
//    W2k 16 + pq 32 + misc ~16 <= 84. (r3 proved <=80 demand -> zero spill.)
__global__ __launch_bounds__(256, 3)
void dvgo_mfma(const float* __restrict__ rays_o, const float* __restrict__ rays_d,
               const float* __restrict__ w0, const float* __restrict__ b0,
               const float* __restrict__ b1, const float* __restrict__ b2,
               const unsigned short* __restrict__ gp,   // packed grid
               const unsigned short* __restrict__ wpk,  // packed weights
               float* __restrict__ out)
{
    __shared__ unsigned short XH[128 * 136]; // union: Xs[128][40] / Hs[128][136]
    __shared__ float shA[128];                // per-chunk (1-alpha)
    __shared__ float wts[128];                // alpha, then final weights
    __shared__ float b0eff[128];
    __shared__ float b1s[128];
    __shared__ float vemb[28];
    __shared__ float red[4][3];
    __shared__ float b2s[3];
    __shared__ float Tcs[3];                  // carry: T before chunk ck; Tcs[2]=ainv
    __shared__ float spart;                   // wave0 scan total

    const int r = blockIdx.x, t = threadIdx.x;
    const int l = t & 63, wv = t >> 6;
    const int col = l & 15, rg = l >> 4;
    const int sl = t >> 1, hf = t & 1;

    const float ox = rays_o[r*3+0], oy = rays_o[r*3+1], oz = rays_o[r*3+2];
    const float dxr = rays_d[r*3+0], dyr = rays_d[r*3+1], dzr = rays_d[r*3+2];
    const float rn = rsqrtf(dxr*dxr + dyr*dyr + dzr*dzr);
    const float vx = dxr*rn, vy = dyr*rn, vz = dzr*rn;

    const uint4* gq = (const uint4*)gp;
    _Float16* XHh = (_Float16*)XH;

    // ---- prefetched gather state (named regs; live range phase A <- prior L1-end) ----
    uint4 pq0, pq1, pq2, pq3, pq4, pq5, pq6, pq7;
    bool inbox_p = false;

    ISSUE_GATHER(0);   // chunk-0 gathers fly during the setup phase below

    // ---- phase 0: vemb, biases ----
    if (t < 27) {
        float val;
        if (t < 3) val = (t == 0) ? vx : ((t == 1) ? vy : vz);
        else {
            int q = t - 3;
            const bool is_sin = q < 12;
            if (!is_sin) q -= 12;
            const int i = q >> 2, p = q & 3;
            const float a = ((i == 0) ? vx : ((i == 1) ? vy : vz)) * (float)(1 << p);
            val = is_sin ? sinf(a) : cosf(a);
        }
        vemb[t] = val;
    }
    if (t < 3)   b2s[t] = b2[t];
    if (t < 128) b1s[t] = b1[t];
    if (t == 0)  Tcs[0] = 1.f;
    __syncthreads();

    if (t < 128) {                       // fold view embedding into layer-0 bias
        float a = b0[t];
        #pragma unroll
        for (int k = 0; k < 27; ++k) a = fmaf(vemb[k], w0[(12 + k) * 128 + t], a);
        b0eff[t] = a;
    }

    const unsigned short* w0p = wpk;
    const unsigned short* w1p = wpk + 8 * 512;
    const unsigned short* w2p = wpk + 40 * 512;

    float pacc = 0.f;   // per-lane weighted-rgb accumulator (cols 0..2 meaningful)

    #pragma unroll 1
    for (int ck = 0; ck < 2; ++ck) {
        // ---- phase A: consume prefetched gathers -> X rows, alpha ----
        {
            unsigned int* xd = (unsigned int*)&XH[sl * 40];
            if (inbox_p) {
                // recompute trilerp fractions (cheap; avoids holding w8 across MLP)
                const int s = ck * 128 + sl;
                const float tp = 0.05f + (1.95f / 255.f) * (float)s;
                const float px = ox + vx*tp, py = oy + vy*tp, pz = oz + vz*tp;
                const float ix = fminf(fmaxf((px + 1.f) * 79.5f, 0.f), 159.f);
                const float iy = fminf(fmaxf((py + 1.f) * 79.5f, 0.f), 159.f);
                const float iz = fminf(fmaxf((pz + 1.f) * 79.5f, 0.f), 159.f);
                const int x0 = min((int)ix, 158), y0 = min((int)iy, 158), z0 = min((int)iz, 158);
                const float fx = ix - x0, fy = iy - y0, fz = iz - z0;
                const float gx = 1.f - fx, gy = 1.f - fy, gz = 1.f - fz;
                float w8[8];
                w8[0]=gx*gy*gz; w8[1]=gx*gy*fz; w8[2]=gx*fy*gz; w8[3]=gx*fy*fz;
                w8[4]=fx*gy*gz; w8[5]=fx*gy*fz; w8[6]=fx*fy*gz; w8[7]=fx*fy*fz;
                h2 ah0 = {0, 0}, ah1 = {0, 0}, ah2 = {0, 0}, ah3 = {0, 0};
                #define CONSUME(Q, WI) {                                             \
                    h2 wc2; wc2.x = (_Float16)w8[WI]; wc2.y = wc2.x;                 \
                    ah0 += __builtin_bit_cast(h2, (Q).x) * wc2;                      \
                    ah1 += __builtin_bit_cast(h2, (Q).y) * wc2;                      \
                    ah2 += __builtin_bit_cast(h2, (Q).z) * wc2;                      \
                    ah3 += __builtin_bit_cast(h2, (Q).w) * wc2;                      \
                }
                CONSUME(pq0, 0); CONSUME(pq1, 1); CONSUME(pq2, 2); CONSUME(pq3, 3);
                CONSUME(pq4, 4); CONSUME(pq5, 5); CONSUME(pq6, 6); CONSUME(pq7, 7);
                #undef CONSUME
                if (hf == 0) {   // slots 0..7 = feat0..7 -> X cols 0..7
                    xd[0] = __builtin_bit_cast(unsigned int, ah0);
                    xd[1] = __builtin_bit_cast(unsigned int, ah1);
                    xd[2] = __builtin_bit_cast(unsigned int, ah2);
                    xd[3] = __builtin_bit_cast(unsigned int, ah3);
                } else {         // slots 8..15 = feat8..11, 0,0,0, dens
                    xd[4] = __builtin_bit_cast(unsigned int, ah0);
                    xd[5] = __builtin_bit_cast(unsigned int, ah1);
                    xd[6] = 0u;                    // cols 12,13
                    xd[7] = 0u;                    // cols 14,15 (NOT dens)
                    const float dv = (float)ah3.y; // slot 15 = density trilerp
                    const float e = expf(dv + ACT_SHIFT_F);
                    const float op = 1.f + e;
                    const float alpha = e / (op + sqrtf(op));   // 1-(1+e)^(-1/2)
                    wts[sl] = alpha;
                    shA[sl] = 1.f - alpha;
                }
            } else {
                if (hf == 0) {
                    xd[0]=0u; xd[1]=0u; xd[2]=0u; xd[3]=0u;
                } else {
                    xd[4]=0u; xd[5]=0u; xd[6]=0u; xd[7]=0u;
                    wts[sl] = 0.f;
                    shA[sl] = 1.f;
                }
            }
            // zero pad cols 16..31 (K=32 tail) — every chunk (union leaves Hs bytes)
            if (hf == 0) { xd[8]=0u;  xd[9]=0u;  xd[10]=0u; xd[11]=0u; }
            else         { xd[12]=0u; xd[13]=0u; xd[14]=0u; xd[15]=0u; }
        }
        __syncthreads();   // Xs/shA/alpha complete

        const int row0 = wv * 32;   // this wave owns sample-rows [row0, row0+32)

        // ---- A0 fragment preload: MUST precede the next barrier (Xs dies here;
        //      Hs writes below would otherwise clobber other waves' unread Xs rows)
        f16x8 A0[2];
        #pragma unroll
        for (int mt = 0; mt < 2; ++mt)
            A0[mt] = *(const f16x8*)(&XH[(row0 + mt * 16 + col) * 40 + rg * 8]);

        // ---- transmittance scan (threads 0..127 = waves 0,1), carry Tcs[ck] ----
        float v = 1.f;
        if (t < 128) {
            v = shA[t];
            #pragma unroll
            for (int off = 1; off < 64; off <<= 1) {
                const float u = __shfl_up(v, off);
                if (l >= off) v *= u;
            }
            if (wv == 0 && l == 63) spart = v;
        }
        __syncthreads();   // spart visible; also: all waves' A0 loads complete
        if (t < 128) {     // scan tail (waves 0-1); waves 2-3 fall through to L0
            float excl = __shfl_up(v, 1);
            if (l == 0) excl = 1.f;
            float E = Tcs[ck];
            const float sp = spart;
            if (wv == 1) E *= sp;
            const float w = wts[t] * E * excl;
            wts[t] = w;
            if (t == 127) Tcs[ck + 1] = Tcs[ck] * sp * v;
        }
        // (no barrier here: wts not read until L2 epilogue; Hs rows wave-private)

        // ---- layer 0: H0 = relu(X*W0 + b0eff), K=32; even/odd B prefetch ----
        {
            #define L0_STEP(B, NT) {                                                  \
                const float bias = b0eff[(NT) * 16 + col];                            \
                _Pragma("unroll")                                                     \
                for (int mt = 0; mt < 2; ++mt) {                                      \
                    f32x4 acc = {bias, bias, bias, bias};                             \
                    acc = __builtin_amdgcn_mfma_f32_16x16x32_f16(A0[mt], B, acc, 0, 0, 0); \
                    _Pragma("unroll")                                                 \
                    for (int q = 0; q < 4; ++q) {                                     \
                        const float vv = fmaxf(acc[q], 0.f);                          \
                        const int row = row0 + mt * 16 + rg * 4 + q;                  \
                        XHh[row * 136 + (NT) * 16 + col] = (_Float16)vv;              \
                    }                                                                 \
                }                                                                     \
            }
            f16x8 Ba = *(const f16x8*)(w0p + l * 8);
            #pragma unroll 1
            for (int nt = 0; nt < 8; nt += 2) {
                const f16x8 Bb = *(const f16x8*)(w0p + (nt + 1) * 512 + l * 8);
                L0_STEP(Ba, nt);
                if (nt < 6) Ba = *(const f16x8*)(w0p + (nt + 2) * 512 + l * 8);
                L0_STEP(Bb, nt + 1);
            }
            #undef L0_STEP
        }

        // ---- layer 1: H1 = relu(H0*W1 + b1), K=128, in-place, even/odd prefetch ----
        {
            f16x8 A1[2][4];
            #pragma unroll
            for (int mt = 0; mt < 2; ++mt)
                #pragma unroll
                for (int ks = 0; ks < 4; ++ks)
                    A1[mt][ks] = *(const f16x8*)(&XH[(row0 + mt * 16 + col) * 136 + ks * 32 + rg * 8]);
            #define L1_STEP(BK, NT) {                                                 \
                const float bias = b1s[(NT) * 16 + col];                              \
                _Pragma("unroll")                                                     \
                for (int mt = 0; mt < 2; ++mt) {                                      \
                    f32x4 acc = {bias, bias, bias, bias};                             \
                    _Pragma("unroll")                                                 \
                    for (int ks = 0; ks < 4; ++ks)                                    \
                        acc = __builtin_amdgcn_mfma_f32_16x16x32_f16(A1[mt][ks], BK[ks], acc, 0, 0, 0); \
                    _Pragma("unroll")                                                 \
                    for (int q = 0; q < 4; ++q) {                                     \
                        const float vv = fmaxf(acc[q], 0.f);                          \
                        const int row = row0 + mt * 16 + rg * 4 + q;                  \
                        XHh[row * 136 + (NT) * 16 + col] = (_Float16)vv;              \
                    }                                                                 \
                }                                                                     \
            }
            f16x8 BkA[4], BkB[4];
            #pragma unroll
            for (int ks = 0; ks < 4; ++ks)
                BkA[ks] = *(const f16x8*)(w1p + ks * 512 + l * 8);
            #pragma unroll 1
            for (int nt = 0; nt < 8; nt += 2) {
                #pragma unroll
                for (int ks = 0; ks < 4; ++ks)
                    BkB[ks] = *(const f16x8*)(w1p + ((nt + 1) * 4 + ks) * 512 + l * 8);
                L1_STEP(BkA, nt);
                if (nt < 6) {
                    #pragma unroll
                    for (int ks = 0; ks < 4; ++ks)
                        BkA[ks] = *(const f16x8*)(w1p + ((nt + 2) * 4 + ks) * 512 + l * 8);
                }
                L1_STEP(BkB, nt + 1);
            }
            #undef L1_STEP
        }

        // ---- next-chunk gather: issued HERE (after L1 freed A1/Bk regs). Latency
        //      hides under W2k load + barrier + L2 + epilogue + next phase-A math.
        if (ck == 0) ISSUE_GATHER(1);

        // ---- W2 fragments: load after L1 (latency overlaps the barrier below) ----
        f16x8 W2k[4];
        #pragma unroll
        for (int ks = 0; ks < 4; ++ks)
            W2k[ks] = *(const f16x8*)(w2p + ks * 512 + l * 8);

        __syncthreads();   // wts (scan tail) visible to all waves; Hs wave-private

        // ---- layer 2 + epilogue: rgb = sigmoid(H1*W2 + b2); pacc += wts*rgb ----
        {
            const float bias2 = (col < 3) ? b2s[col] : 0.f;
            #pragma unroll
            for (int mt = 0; mt < 2; ++mt) {
                f16x8 A2[4];
                #pragma unroll
                for (int ks = 0; ks < 4; ++ks)
                    A2[ks] = *(const f16x8*)(&XH[(row0 + mt * 16 + col) * 136 + ks * 32 + rg * 8]);
                f32x4 acc = {bias2, bias2, bias2, bias2};
                #pragma unroll
                for (int ks = 0; ks < 4; ++ks)
                    acc = __builtin_amdgcn_mfma_f32_16x16x32_f16(A2[ks], W2k[ks], acc, 0, 0, 0);
                #pragma unroll
                for (int q = 0; q < 4; ++q) {
                    const float sg = 1.f / (1.f + expf(-acc[q]));
                    const int srow = row0 + mt * 16 + rg * 4 + q;
                    pacc = fmaf(wts[srow], sg, pacc);
                }
            }
        }
        __syncthreads();   // XH/shA/wts safe to rewrite next chunk
    }

    // reduce pacc over the 4 row-groups (lanes sharing a column)
    pacc += __shfl_xor(pacc, 16);
    pacc += __shfl_xor(pacc, 32);
    if (rg == 0 && col < 3) red[wv][col] = pacc;
    __syncthreads();
    if (t < 3) out[r * 3 + t] = red[0][t] + red[1][t] + red[2][t] + red[3][t] + Tcs[2];
}

// ---------------- fallback (round-1 kernel) if ws too small ----------------
__global__ __launch_bounds__(256, 2)
void dvgo_render(const float* __restrict__ rays_o, const float* __restrict__ rays_d,
                 const float* __restrict__ dens, const float* __restrict__ k0,
                 const float* __restrict__ w0, const float* __restrict__ b0,
                 const float* __restrict__ w1, const float* __restrict__ b1,
                 const float* __restrict__ w2, const float* __restrict__ b2,
                 float* __restrict__ out)
{
    __shared__ float xs[256 * 40];
    __shared__ float sh[256];
    __shared__ float wts[256];
    __shared__ float h0s[2][128];
    __shared__ float red[2][2][3];
    __shared__ float rgbacc[6];
    __shared__ float ainv_sh;

    const int r = blockIdx.x, tid = threadIdx.x;
    {
        const int s = tid;
        const float ox = rays_o[r*3+0], oy = rays_o[r*3+1], oz = rays_o[r*3+2];
        const float dxr = rays_d[r*3+0], dyr = rays_d[r*3+1], dzr = rays_d[r*3+2];
        const float rn = rsqrtf(dxr*dxr + dyr*dyr + dzr*dzr);
        const float vx = dxr*rn, vy = dyr*rn, vz = dzr*rn;
        const float t = 0.05f + 1.95f * (1.0f/255.0f) * (float)s;
        const float px = ox + vx*t, py = oy + vy*t, pz = oz + vz*t;
        const bool inbox = (px >= -1.f) && (px <= 1.f) && (py >= -1.f) && (py <= 1.f) &&
                           (pz >= -1.f) && (pz <= 1.f);
        const float ix = fminf(fmaxf((px + 1.f) * 79.5f, 0.f), 159.f);
        const float iy = fminf(fmaxf((py + 1.f) * 79.5f, 0.f), 159.f);
        const float iz = fminf(fmaxf((pz + 1.f) * 79.5f, 0.f), 159.f);
        const int x0 = min((int)ix, 158), y0 = min((int)iy, 158), z0 = min((int)iz, 158);
        const float fx = ix - x0, fy = iy - y0, fz = iz - z0;
        const float gx = 1.f - fx, gy = 1.f - fy, gz = 1.f - fz;
        const int DX = 25600, DY = 160;
        const int base = (x0*160 + y0)*160 + z0;
        const float w000=gx*gy*gz, w100=fx*gy*gz, w010=gx*fy*gz, w001=gx*gy*fz;
        const float w110=fx*fy*gz, w101=fx*gy*fz, w011=gx*fy*fz, w111=fx*fy*fz;
        float alpha = 0.f;
        if (inbox) {
            const float d = dens[base]*w000 + dens[base+DX]*w100 + dens[base+DY]*w010 +
                            dens[base+1]*w001 + dens[base+DX+DY]*w110 + dens[base+DX+1]*w101 +
                            dens[base+DY+1]*w011 + dens[base+DX+DY+1]*w111;
            const float e = expf(d + ACT_SHIFT_F);
            const float op = 1.f + e;
            alpha = e / (op + sqrtf(op));
        }
        sh[s] = 1.f - alpha;
        __syncthreads();
        #pragma unroll
        for (int off = 1; off < 256; off <<= 1) {
            const float v = (s >= off) ? sh[s - off] : 1.f;
            __syncthreads();
            sh[s] *= v;
            __syncthreads();
        }
        wts[s] = alpha * ((s == 0) ? 1.f : sh[s-1]);
        if (s == 255) ainv_sh = sh[255];
        if (s < 6) rgbacc[s] = 0.f;
        float* xrow = &xs[s*40];
        if (inbox) {
            #pragma unroll
            for (int c = 0; c < 12; ++c) {
                const float* g = k0 + c*4096000 + base;
                xrow[c] = g[0]*w000 + g[DX]*w100 + g[DY]*w010 + g[1]*w001 +
                          g[DX+DY]*w110 + g[DX+1]*w101 + g[DY+1]*w011 + g[DX+DY+1]*w111;
            }
        } else {
            #pragma unroll
            for (int c = 0; c < 12; ++c) xrow[c] = 0.f;
        }
        xrow[12]=vx; xrow[13]=vy; xrow[14]=vz;
        const float v3[3] = {vx, vy, vz};
        #pragma unroll
        for (int i = 0; i < 3; ++i)
            #pragma unroll
            for (int p = 0; p < 4; ++p) {
                const float a = v3[i] * (float)(1 << p);
                xrow[15 + i*4 + p] = sinf(a);
                xrow[27 + i*4 + p] = cosf(a);
            }
        xrow[39] = 0.f;
    }
    __syncthreads();
    const int j = tid & 127, sb = tid >> 7;
    float w0c[40];
    #pragma unroll
    for (int k = 0; k < 39; ++k) w0c[k] = w0[k*128 + j];
    w0c[39] = 0.f;
    float w1c[128];
    #pragma unroll
    for (int k = 0; k < 128; ++k) w1c[k] = w1[k*128 + j];
    const float b0j = b0[j], b1j = b1[j];
    const float w2r0 = w2[j*3+0], w2r1 = w2[j*3+1], w2r2 = w2[j*3+2];
    const float b20 = b2[0], b21 = b2[1], b22 = b2[2];
    const int lane = tid & 63, halfw = (tid >> 6) & 1;
    for (int it = 0; it < 128; ++it) {
        const int s = it*2 + sb;
        const float4* xrow4 = (const float4*)(&xs[s*40]);
        float acc = b0j;
        #pragma unroll
        for (int q = 0; q < 10; ++q) {
            const float4 v = xrow4[q];
            acc = fmaf(v.x, w0c[q*4+0], acc); acc = fmaf(v.y, w0c[q*4+1], acc);
            acc = fmaf(v.z, w0c[q*4+2], acc); acc = fmaf(v.w, w0c[q*4+3], acc);
        }
        h0s[sb][j] = fmaxf(acc, 0.f);
        __syncthreads();
        float acc1 = b1j;
        const float4* h4 = (const float4*)(&h0s[sb][0]);
        #pragma unroll
        for (int q = 0; q < 32; ++q) {
            const float4 v = h4[q];
            acc1 = fmaf(v.x, w1c[q*4+0], acc1); acc1 = fmaf(v.y, w1c[q*4+1], acc1);
            acc1 = fmaf(v.z, w1c[q*4+2], acc1); acc1 = fmaf(v.w, w1c[q*4+3], acc1);
        }
        const float hv = fmaxf(acc1, 0.f);
        float p0 = hv*w2r0, p1 = hv*w2r1, p2 = hv*w2r2;
        #pragma unroll
        for (int off = 32; off > 0; off >>= 1) {
            p0 += __shfl_down(p0, off); p1 += __shfl_down(p1, off); p2 += __shfl_down(p2, off);
        }
        if (lane == 0) { red[sb][halfw][0]=p0; red[sb][halfw][1]=p1; red[sb][halfw][2]=p2; }
        __syncthreads();
        if (tid == sb*128) {
            const float r0 = red[sb][0][0]+red[sb][1][0]+b20;
            const float r1 = red[sb][0][1]+red[sb][1][1]+b21;
            const float r2 = red[sb][0][2]+red[sb][1][2]+b22;
            const float wgt = wts[s];
            rgbacc[sb*3+0] += wgt / (1.f + expf(-r0));
            rgbacc[sb*3+1] += wgt / (1.f + expf(-r1));
            rgbacc[sb*3+2] += wgt / (1.f + expf(-r2));
        }
    }
    __syncthreads();
    if (tid < 3) out[r*3 + tid] = rgbacc[tid] + rgbacc[3 + tid] + ainv_sh;
}

extern "C" void kernel_launch(void* const* d_in, const int* in_sizes, int n_in,
                              void* d_out, int out_size, void* d_ws, size_t ws_size,
                              hipStream_t stream)
{
    const float* rays_o = (const float*)d_in[0];
    const float* rays_d = (const float*)d_in[1];
    const float* dens   = (const float*)d_in[2];
    const float* k0     = (const float*)d_in[3];
    const float* w0     = (const float*)d_in[4];
    const float* b0     = (const float*)d_in[5];
    const float* w1     = (const float*)d_in[6];
    const float* b1     = (const float*)d_in[7];
    const float* w2     = (const float*)d_in[8];
    const float* b2     = (const float*)d_in[9];
    float* out = (float*)d_out;
    const int N = in_sizes[0] / 3;

    if (ws_size >= WS_NEED) {
        unsigned short* gp  = (unsigned short*)d_ws;
        unsigned short* wpk = (unsigned short*)((char*)d_ws + W0P_OFF);
        repack_all<<<dim3(4011), dim3(256), 0, stream>>>(dens, k0, w0, w1, w2, gp, wpk);
        dvgo_mfma<<<dim3(N), dim3(256), 0, stream>>>(rays_o, rays_d, w0, b0, b1, b2,
                                                     gp, wpk, out);
    } else {
        dvgo_render<<<dim3(N), dim3(256), 0, stream>>>(rays_o, rays_d, dens, k0,
                                                       w0, b0, w1, b1, w2, b2, out);
    }
}

// Round 9
// 437.672 us; speedup vs baseline: 1.0453x; 1.0408x over previous
//
#include <hip/hip_runtime.h>
#include <hip/hip_bf16.h>
#include <math.h>

#define ACT_SHIFT_F (-13.8155095579637744f)
#define GRID_VOX 4096000
#define GP_BYTES  (GRID_VOX * 32)          // bf16 x16 channels per voxel
#define W0P_OFF   GP_BYTES                 // 8 frags  * 1024B
#define W1P_OFF   (W0P_OFF + 8 * 1024)     // 32 frags * 1024B
#define W2P_OFF   (W1P_OFF + 32 * 1024)    // 4 frags  * 1024B
#define WS_NEED   ((size_t)(W2P_OFF + 4 * 1024))

typedef __bf16 bf16x8 __attribute__((ext_vector_type(8)));
typedef __bf16 bf16x2 __attribute__((ext_vector_type(2)));
typedef float  f32x4  __attribute__((ext_vector_type(4)));
typedef float  fv4    __attribute__((ext_vector_type(4)));   // clang vector (nontemporal-ok)

__device__ __forceinline__ unsigned short f2bf(float x) {   // RNE
    unsigned int u = __float_as_uint(x);
    u += 0x7fffu + ((u >> 16) & 1u);
    return (unsigned short)(u >> 16);
}
// paired f32->bf16 store (compiler emits v_cvt_pk_bf16_f32)
__device__ __forceinline__ void st_bf2(unsigned short* p, float lo, float hi) {
    bf16x2 v; v.x = (__bf16)lo; v.y = (__bf16)hi;
    *(bf16x2*)p = v;
}
// truncation pack: a -> low16, b -> high16 (grid only; |rel err| <= 2^-8)
__device__ __forceinline__ unsigned int packtr(float a, float b) {
    return (__float_as_uint(a) >> 16) | (__float_as_uint(b) & 0xffff0000u);
}
#define UNPK(u, lo, hi) { lo = __uint_as_float((u) << 16); hi = __uint_as_float((u) & 0xffff0000u); }

// ---------------- repack (fused): grid -> interleaved bf16 [vox][16]; W -> B-frags ----
__global__ void repack_all(const float* __restrict__ dens, const float* __restrict__ k0,
                           const float* __restrict__ w0, const float* __restrict__ w1,
                           const float* __restrict__ w2,
                           unsigned short* __restrict__ gp, unsigned short* __restrict__ wp)
{
    const int b = blockIdx.x;
    if (b < 4000) {
        const int v4 = b * 1024 + threadIdx.x * 4;       // 4 consecutive voxels
        const fv4 d4 = __builtin_nontemporal_load((const fv4*)(dens + v4));
        fv4 c4[12];
        #pragma unroll
        for (int c = 0; c < 12; ++c)
            c4[c] = __builtin_nontemporal_load((const fv4*)(k0 + (size_t)c * GRID_VOX + v4));
        uint4* dst = (uint4*)(gp + (size_t)v4 * 16);
        #pragma unroll
        for (int j = 0; j < 4; ++j) {
            const float* cj = &((const float*)c4)[j];     // c4[c] component j at cj[4*c]
            uint4 q0, q1;
            q0.x = packtr(d4[j],    cj[0]);
            q0.y = packtr(cj[4*1],  cj[4*2]);
            q0.z = packtr(cj[4*3],  cj[4*4]);
            q0.w = packtr(cj[4*5],  cj[4*6]);
            q1.x = packtr(cj[4*7],  cj[4*8]);
            q1.y = packtr(cj[4*9],  cj[4*10]);
            q1.z = packtr(cj[4*11], 0.f);
            q1.w = 0u;
            dst[j*2 + 0] = q0;
            dst[j*2 + 1] = q1;
        }
        return;
    }
    // ---- weight repack: B-frag (16x16x32): lane l holds B[k=(l>>4)*8+j][n=l&15] ----
    const int t = (b - 4000) * 256 + threadIdx.x;
    if (t >= 44 * 64) return;
    const int f = t >> 6, l = t & 63;
    const int n16 = l & 15, kg = l >> 4;
    unsigned short v[8];
    if (f < 8) {                       // W0: ntile=f, K=32 (feature rows 0..11 real)
        const int n = f * 16 + n16;
        #pragma unroll
        for (int j = 0; j < 8; ++j) {
            const int k = kg * 8 + j;
            v[j] = (k < 12) ? f2bf(w0[k * 128 + n]) : (unsigned short)0;
        }
    } else if (f < 40) {               // W1: frag (nt, ks)
        const int ff = f - 8, nt = ff >> 2, ks = ff & 3;
        const int n = nt * 16 + n16;
        #pragma unroll
        for (int j = 0; j < 8; ++j) {
            const int k = ks * 32 + kg * 8 + j;
            v[j] = f2bf(w1[k * 128 + n]);
        }
    } else {                           // W2: N=16 (cols 0..2 real), frag ks
        const int ks = f - 40;
        #pragma unroll
        for (int j = 0; j < 8; ++j) {
            const int k = ks * 32 + kg * 8 + j;
            v[j] = (n16 < 3) ? f2bf(w2[k * 3 + n16]) : (unsigned short)0;
        }
    }
    uint4 q;
    q.x = v[0] | (v[1] << 16); q.y = v[2] | (v[3] << 16);
    q.z = v[4] | (v[5] << 16); q.w = v[6] | (v[7] << 16);
    *(uint4*)(wp + f * 512 + l * 8) = q;
}

// voxel-corner offsets (in voxel units; *2 applied at use site for uint4 pairs)
#define OFF_C0 0
#define OFF_C1 1
#define OFF_C2 160
#define OFF_C3 161
#define OFF_C4 25600
#define OFF_C5 25601
#define OFF_C6 25760
#define OFF_C7 25761

// issue the 8 corner loads for chunk CK into named regs pq0..pq7
#define ISSUE_GATHER(CK) do {                                                        \
    const int s_ = (CK) * 128 + sl;                                                  \
    const float tp_ = 0.05f + (1.95f / 255.f) * (float)s_;                           \
    const float px_ = ox + vx*tp_, py_ = oy + vy*tp_, pz_ = oz + vz*tp_;             \
    inbox_p = (px_ >= -1.f) & (px_ <= 1.f) & (py_ >= -1.f) & (py_ <= 1.f) &          \
              (pz_ >= -1.f) & (pz_ <= 1.f);                                          \
    if (inbox_p) {                                                                   \
        const float ix_ = fminf(fmaxf((px_ + 1.f) * 79.5f, 0.f), 159.f);             \
        const float iy_ = fminf(fmaxf((py_ + 1.f) * 79.5f, 0.f), 159.f);             \
        const float iz_ = fminf(fmaxf((pz_ + 1.f) * 79.5f, 0.f), 159.f);             \
        const int x0_ = min((int)ix_, 158), y0_ = min((int)iy_, 158),                \
                  z0_ = min((int)iz_, 158);                                          \
        const size_t b_ = (size_t)((x0_ * 160 + y0_) * 160 + z0_) * 2 + hf;          \
        pq0 = gq[b_ + OFF_C0*2]; pq1 = gq[b_ + OFF_C1*2];                            \
        pq2 = gq[b_ + OFF_C2*2]; pq3 = gq[b_ + OFF_C3*2];                            \
        pq4 = gq[b_ + OFF_C4*2]; pq5 = gq[b_ + OFF_C5*2];                            \
        pq6 = gq[b_ + OFF_C6*2]; pq7 = gq[b_ + OFF_C7*2];                            \
    }                                                                                \
} while (0)

// ---------------- main render: one block per ray ----------------
// Base: the round-4 kernel (best measured: 117 us, bf16, one-ahead weight
// prefetch, per-lane b16 epilogue stores, barrier before L2 only).
// Two demand-cut changes (r6/r7 proved attributes/placement don't bind; only
// total peak-window demand does — r4 overshot the 84-reg grant by ~9 dwords):
//  - L1 split into two sequential mt passes: A1 32 -> 16 regs in the L1 window.
//    W1 frags fetched twice per wave (L2-resident, hidden by one-ahead prefetch);
//    row halves are disjoint so the in-place Hs update stays race-free.
//  - W2k hoist moved AFTER L1 (r6-verified safe): -16 regs through the L1 peak.
__global__ __launch_bounds__(256, 3)
void dvgo_mfma(const float* __restrict__ rays_o, const float* __restrict__ rays_d,
               const float* __restrict__ w0, const float* __restrict__ b0,
               const float* __restrict__ b1, const float* __restrict__ b2,
               const unsigned short* __restrict__ gp,   // packed grid
               const unsigned short* __restrict__ wpk,  // packed weights
               float* __restrict__ out)
{
    __shared__ unsigned short XH[128 * 136]; // union: Xs[128][40] / Hs[128][136]
    __shared__ float shA[128];                // per-chunk (1-alpha)
    __shared__ float wts[128];                // alpha, then final weights
    __shared__ float b0eff[128];
    __shared__ float b1s[128];
    __shared__ float vemb[28];
    __shared__ float red[4][3];
    __shared__ float b2s[3];
    __shared__ float Tcs[3];                  // carry: T before chunk ck; Tcs[2]=ainv
    __shared__ float spart;                   // wave0 scan total

    const int r = blockIdx.x, t = threadIdx.x;
    const int l = t & 63, wv = t >> 6;
    const int col = l & 15, rg = l >> 4;
    const int sl = t >> 1, hf = t & 1;

    const float ox = rays_o[r*3+0], oy = rays_o[r*3+1], oz = rays_o[r*3+2];
    const float dxr = rays_d[r*3+0], dyr = rays_d[r*3+1], dzr = rays_d[r*3+2];
    const float rn = rsqrtf(dxr*dxr + dyr*dyr + dzr*dzr);
    const float vx = dxr*rn, vy = dyr*rn, vz = dzr*rn;

    const uint4* gq = (const uint4*)gp;

    // ---- prefetched gather state (named regs, held across the MLP) ----
    uint4 pq0, pq1, pq2, pq3, pq4, pq5, pq6, pq7;
    bool inbox_p = false;

    ISSUE_GATHER(0);   // chunk-0 gathers fly during the setup phase below

    // ---- phase 0: vemb, biases ----
    if (t < 27) {
        float val;
        if (t < 3) val = (t == 0) ? vx : ((t == 1) ? vy : vz);
        else {
            int q = t - 3;
            const bool is_sin = q < 12;
            if (!is_sin) q -= 12;
            const int i = q >> 2, p = q & 3;
            const float a = ((i == 0) ? vx : ((i == 1) ? vy : vz)) * (float)(1 << p);
            val = is_sin ? sinf(a) : cosf(a);
        }
        vemb[t] = val;
    }
    if (t < 3)   b2s[t] = b2[t];
    if (t < 128) b1s[t] = b1[t];
    if (t == 0)  Tcs[0] = 1.f;
    __syncthreads();

    if (t < 128) {                       // fold view embedding into layer-0 bias
        float a = b0[t];
        #pragma unroll
        for (int k = 0; k < 27; ++k) a = fmaf(vemb[k], w0[(12 + k) * 128 + t], a);
        b0eff[t] = a;
    }

    const unsigned short* w0p = wpk;
    const unsigned short* w1p = wpk + 8 * 512;
    const unsigned short* w2p = wpk + 40 * 512;

    float pacc = 0.f;   // per-lane weighted-rgb accumulator (cols 0..2 meaningful)

    #pragma unroll 1
    for (int ck = 0; ck < 2; ++ck) {
        // ---- phase A: consume prefetched gathers -> X rows, alpha ----
        {
            unsigned short* xrow = &XH[sl * 40];
            unsigned int*  xd   = (unsigned int*)xrow;
            if (inbox_p) {
                // recompute trilerp fractions (cheap; avoids holding w8 across MLP)
                const int s = ck * 128 + sl;
                const float tp = 0.05f + (1.95f / 255.f) * (float)s;
                const float px = ox + vx*tp, py = oy + vy*tp, pz = oz + vz*tp;
                const float ix = fminf(fmaxf((px + 1.f) * 79.5f, 0.f), 159.f);
                const float iy = fminf(fmaxf((py + 1.f) * 79.5f, 0.f), 159.f);
                const float iz = fminf(fmaxf((pz + 1.f) * 79.5f, 0.f), 159.f);
                const int x0 = min((int)ix, 158), y0 = min((int)iy, 158), z0 = min((int)iz, 158);
                const float fx = ix - x0, fy = iy - y0, fz = iz - z0;
                const float gx = 1.f - fx, gy = 1.f - fy, gz = 1.f - fz;
                float w8[8];
                w8[0]=gx*gy*gz; w8[1]=gx*gy*fz; w8[2]=gx*fy*gz; w8[3]=gx*fy*fz;
                w8[4]=fx*gy*gz; w8[5]=fx*gy*fz; w8[6]=fx*fy*gz; w8[7]=fx*fy*fz;
                float a0=0,a1=0,a2=0,a3=0,a4=0,a5=0,a6=0,a7=0;
                #define CONSUME(Q, WI) {                                             \
                    float f0,f1,f2,f3,f4,f5,f6,f7;                                   \
                    UNPK((Q).x, f0, f1); UNPK((Q).y, f2, f3);                        \
                    UNPK((Q).z, f4, f5); UNPK((Q).w, f6, f7);                        \
                    const float wc = w8[WI];                                         \
                    a0=fmaf(wc,f0,a0); a1=fmaf(wc,f1,a1); a2=fmaf(wc,f2,a2);         \
                    a3=fmaf(wc,f3,a3); a4=fmaf(wc,f4,a4); a5=fmaf(wc,f5,a5);         \
                    a6=fmaf(wc,f6,a6); a7=fmaf(wc,f7,a7);                            \
                }
                CONSUME(pq0, 0); CONSUME(pq1, 1); CONSUME(pq2, 2); CONSUME(pq3, 3);
                CONSUME(pq4, 4); CONSUME(pq5, 5); CONSUME(pq6, 6); CONSUME(pq7, 7);
                #undef CONSUME
                if (hf == 0) {   // slots 0..7 = [dens, feat0..6]; a0 = density trilerp
                    st_bf2(&xrow[0], a1, a2);
                    st_bf2(&xrow[2], a3, a4);
                    st_bf2(&xrow[4], a5, a6);
                    *(__bf16*)&xrow[6] = (__bf16)a7;
                    const float e = expf(a0 + ACT_SHIFT_F);
                    const float op = 1.f + e;
                    const float alpha = e / (op + sqrtf(op));   // 1-(1+e)^(-1/2)
                    wts[sl] = alpha;
                    shA[sl] = 1.f - alpha;
                } else {         // slots 8..15 = [feat7..11, pad] -> x cols 7..11
                    *(__bf16*)&xrow[7] = (__bf16)a0;
                    st_bf2(&xrow[8],  a1, a2);
                    st_bf2(&xrow[10], a3, a4);
                }
            } else {
                if (hf == 0) {
                    xd[0]=0u; xd[1]=0u; xd[2]=0u; xrow[6]=0;
                    wts[sl] = 0.f;
                    shA[sl] = 1.f;
                } else {
                    xrow[7]=0; xd[4]=0u; xd[5]=0u;
                }
            }
            // zero pad cols 12..31 (k tail of the K=32 MFMA) — every chunk, since
            // the union leaves last chunk's Hs bytes here
            if (hf == 0) { xd[6]=0u; xd[7]=0u; xd[8]=0u; xd[9]=0u; xd[10]=0u; }
            else         { xd[11]=0u; xd[12]=0u; xd[13]=0u; xd[14]=0u; xd[15]=0u; }
            if (ck == 0) ISSUE_GATHER(1);   // chunk-1 loads hide under scan + MLP
        }
        __syncthreads();   // Xs/shA/alpha complete

        const int row0 = wv * 32;   // this wave owns sample-rows [row0, row0+32)

        // ---- A0 fragment preload: MUST precede the next barrier (Xs dies here;
        //      Hs writes below would otherwise clobber other waves' unread Xs rows)
        bf16x8 A0[2];
        #pragma unroll
        for (int mt = 0; mt < 2; ++mt)
            A0[mt] = *(const bf16x8*)(&XH[(row0 + mt * 16 + col) * 40 + rg * 8]);

        // ---- transmittance scan (threads 0..127 = waves 0,1), carry Tcs[ck] ----
        float v = 1.f;
        if (t < 128) {
            v = shA[t];
            #pragma unroll
            for (int off = 1; off < 64; off <<= 1) {
                const float u = __shfl_up(v, off);
                if (l >= off) v *= u;
            }
            if (wv == 0 && l == 63) spart = v;
        }
        __syncthreads();   // spart visible; also: all waves' A0 loads complete
        if (t < 128) {     // scan tail (waves 0-1); waves 2-3 fall through to L0
            float excl = __shfl_up(v, 1);
            if (l == 0) excl = 1.f;
            float E = Tcs[ck];
            const float sp = spart;
            if (wv == 1) E *= sp;
            const float w = wts[t] * E * excl;
            wts[t] = w;
            if (t == 127) Tcs[ck + 1] = Tcs[ck] * sp * v;
        }
        // (no barrier here: wts not read until L2 epilogue; Hs rows wave-private)

        // ---- layer 0: H0 = relu(X*W0 + b0eff), K=32; one-ahead B prefetch ----
        {
            bf16x8 Bc = *(const bf16x8*)(w0p + l * 8);
            #pragma unroll 1
            for (int nt = 0; nt < 8; ++nt) {
                const bf16x8 B = Bc;
                if (nt < 7) Bc = *(const bf16x8*)(w0p + (nt + 1) * 512 + l * 8);
                const float bias = b0eff[nt * 16 + col];
                #pragma unroll
                for (int mt = 0; mt < 2; ++mt) {
                    f32x4 acc = {0.f, 0.f, 0.f, 0.f};
                    acc = __builtin_amdgcn_mfma_f32_16x16x32_bf16(A0[mt], B, acc, 0, 0, 0);
                    #pragma unroll
                    for (int q = 0; q < 4; ++q) {
                        const float vv = fmaxf(acc[q] + bias, 0.f);
                        const int row = row0 + mt * 16 + rg * 4 + q;
                        *(__bf16*)&XH[row * 136 + nt * 16 + col] = (__bf16)vv;
                    }
                }
            }
        }

        // ---- layer 1: H1 = relu(H0*W1 + b1), K=128, in-place, split by mt ----
        // (mt halves touch disjoint row bands [row0+mt*16, +16), so the in-place
        //  read-then-write stays safe; A1 halved to 16 regs in this window)
        #pragma unroll 1
        for (int mt = 0; mt < 2; ++mt) {
            bf16x8 A1[4];
            #pragma unroll
            for (int ks = 0; ks < 4; ++ks)
                A1[ks] = *(const bf16x8*)(&XH[(row0 + mt * 16 + col) * 136 + ks * 32 + rg * 8]);
            bf16x8 Bk[4];
            #pragma unroll
            for (int ks = 0; ks < 4; ++ks)
                Bk[ks] = *(const bf16x8*)(w1p + ks * 512 + l * 8);
            #pragma unroll 1
            for (int nt = 0; nt < 8; ++nt) {
                bf16x8 Bn[4];
                const int ntn = (nt < 7) ? nt + 1 : 7;
                #pragma unroll
                for (int ks = 0; ks < 4; ++ks)
                    Bn[ks] = *(const bf16x8*)(w1p + (ntn * 4 + ks) * 512 + l * 8);
                const float bias = b1s[nt * 16 + col];
                f32x4 acc = {0.f, 0.f, 0.f, 0.f};
                #pragma unroll
                for (int ks = 0; ks < 4; ++ks)
                    acc = __builtin_amdgcn_mfma_f32_16x16x32_bf16(A1[ks], Bk[ks], acc, 0, 0, 0);
                #pragma unroll
                for (int q = 0; q < 4; ++q) {
                    const float vv = fmaxf(acc[q] + bias, 0.f);
                    const int row = row0 + mt * 16 + rg * 4 + q;
                    *(__bf16*)&XH[row * 136 + nt * 16 + col] = (__bf16)vv;
                }
                #pragma unroll
                for (int ks = 0; ks < 4; ++ks) Bk[ks] = Bn[ks];
            }
        }

        // ---- W2 fragments: load AFTER L1 (latency overlaps the barrier below) ----
        bf16x8 W2k[4];
        #pragma unroll
        for (int ks = 0; ks < 4; ++ks)
            W2k[ks] = *(const bf16x8*)(w2p + ks * 512 + l * 8);

        __syncthreads();   // wts (scan tail) visible to all waves; Hs wave-private

        // ---- layer 2 + epilogue: rgb = sigmoid(H1*W2 + b2); pacc += wts*rgb ----
        {
            const float bias2 = (col < 3) ? b2s[col] : 0.f;
            #pragma unroll
            for (int mt = 0; mt < 2; ++mt) {
                bf16x8 A2[4];
                #pragma unroll
                for (int ks = 0; ks < 4; ++ks)
                    A2[ks] = *(const bf16x8*)(&XH[(row0 + mt * 16 + col) * 136 + ks * 32 + rg * 8]);
                f32x4 acc = {0.f, 0.f, 0.f, 0.f};
                #pragma unroll
                for (int ks = 0; ks < 4; ++ks)
                    acc = __builtin_amdgcn_mfma_f32_16x16x32_bf16(A2[ks], W2k[ks], acc, 0, 0, 0);
                #pragma unroll
                for (int q = 0; q < 4; ++q) {
                    const float rv = acc[q] + bias2;
                    const float sg = 1.f / (1.f + expf(-rv));
                    const int srow = row0 + mt * 16 + rg * 4 + q;
                    pacc = fmaf(wts[srow], sg, pacc);
                }
            }
        }
        __syncthreads();   // XH/shA/wts safe to rewrite next chunk
    }

    // reduce pacc over the 4 row-groups (lanes sharing a column)
    pacc += __shfl_xor(pacc, 16);
    pacc += __shfl_xor(pacc, 32);
    if (rg == 0 && col < 3) red[wv][col] = pacc;
    __syncthreads();
    if (t < 3) out[r * 3 + t] = red[0][t] + red[1][t] + red[2][t] + red[3][t] + Tcs[2];
}

// ---------------- fallback (round-1 kernel) if ws too small ----------------
__global__ __launch_bounds__(256, 2)
void dvgo_render(const float* __restrict__ rays_o, const float* __restrict__ rays_d,
                 const float* __restrict__ dens, const float* __restrict__ k0,
                 const float* __restrict__ w0, const float* __restrict__ b0,
                 const float* __restrict__ w1, const float* __restrict__ b1,
                 const float* __restrict__ w2, const float* __restrict__ b2,
                 float* __restrict__ out)
{
    __shared__ float xs[256 * 40];
    __shared__ float sh[256];
    __shared__ float wts[256];
    __shared__ float h0s[2][128];
    __shared__ float red[2][2][3];
    __shared__ float rgbacc[6];
    __shared__ float ainv_sh;

    const int r = blockIdx.x, tid = threadIdx.x;
    {
        const int s = tid;
        const float ox = rays_o[r*3+0], oy = rays_o[r*3+1], oz = rays_o[r*3+2];
        const float dxr = rays_d[r*3+0], dyr = rays_d[r*3+1], dzr = rays_d[r*3+2];
        const float rn = rsqrtf(dxr*dxr + dyr*dyr + dzr*dzr);
        const float vx = dxr*rn, vy = dyr*rn, vz = dzr*rn;
        const float t = 0.05f + 1.95f * (1.0f/255.0f) * (float)s;
        const float px = ox + vx*t, py = oy + vy*t, pz = oz + vz*t;
        const bool inbox = (px >= -1.f) && (px <= 1.f) && (py >= -1.f) && (py <= 1.f) &&
                           (pz >= -1.f) && (pz <= 1.f);
        const float ix = fminf(fmaxf((px + 1.f) * 79.5f, 0.f), 159.f);
        const float iy = fminf(fmaxf((py + 1.f) * 79.5f, 0.f), 159.f);
        const float iz = fminf(fmaxf((pz + 1.f) * 79.5f, 0.f), 159.f);
        const int x0 = min((int)ix, 158), y0 = min((int)iy, 158), z0 = min((int)iz, 158);
        const float fx = ix - x0, fy = iy - y0, fz = iz - z0;
        const float gx = 1.f - fx, gy = 1.f - fy, gz = 1.f - fz;
        const int DX = 25600, DY = 160;
        const int base = (x0*160 + y0)*160 + z0;
        const float w000=gx*gy*gz, w100=fx*gy*gz, w010=gx*fy*gz, w001=gx*gy*fz;
        const float w110=fx*fy*gz, w101=fx*gy*fz, w011=gx*fy*fz, w111=fx*fy*fz;
        float alpha = 0.f;
        if (inbox) {
            const float d = dens[base]*w000 + dens[base+DX]*w100 + dens[base+DY]*w010 +
                            dens[base+1]*w001 + dens[base+DX+DY]*w110 + dens[base+DX+1]*w101 +
                            dens[base+DY+1]*w011 + dens[base+DX+DY+1]*w111;
            const float e = expf(d + ACT_SHIFT_F);
            const float op = 1.f + e;
            alpha = e / (op + sqrtf(op));
        }
        sh[s] = 1.f - alpha;
        __syncthreads();
        #pragma unroll
        for (int off = 1; off < 256; off <<= 1) {
            const float v = (s >= off) ? sh[s - off] : 1.f;
            __syncthreads();
            sh[s] *= v;
            __syncthreads();
        }
        wts[s] = alpha * ((s == 0) ? 1.f : sh[s-1]);
        if (s == 255) ainv_sh = sh[255];
        if (s < 6) rgbacc[s] = 0.f;
        float* xrow = &xs[s*40];
        if (inbox) {
            #pragma unroll
            for (int c = 0; c < 12; ++c) {
                const float* g = k0 + c*4096000 + base;
                xrow[c] = g[0]*w000 + g[DX]*w100 + g[DY]*w010 + g[1]*w001 +
                          g[DX+DY]*w110 + g[DX+1]*w101 + g[DY+1]*w011 + g[DX+DY+1]*w111;
            }
        } else {
            #pragma unroll
            for (int c = 0; c < 12; ++c) xrow[c] = 0.f;
        }
        xrow[12]=vx; xrow[13]=vy; xrow[14]=vz;
        const float v3[3] = {vx, vy, vz};
        #pragma unroll
        for (int i = 0; i < 3; ++i)
            #pragma unroll
            for (int p = 0; p < 4; ++p) {
                const float a = v3[i] * (float)(1 << p);
                xrow[15 + i*4 + p] = sinf(a);
                xrow[27 + i*4 + p] = cosf(a);
            }
        xrow[39] = 0.f;
    }
    __syncthreads();
    const int j = tid & 127, sb = tid >> 7;
    float w0c[40];
    #pragma unroll
    for (int k = 0; k < 39; ++k) w0c[k] = w0[k*128 + j];
    w0c[39] = 0.f;
    float w1c[128];
    #pragma unroll
    for (int k = 0; k < 128; ++k) w1c[k] = w1[k*128 + j];
    const float b0j = b0[j], b1j = b1[j];
    const float w2r0 = w2[j*3+0], w2r1 = w2[j*3+1], w2r2 = w2[j*3+2];
    const float b20 = b2[0], b21 = b2[1], b22 = b2[2];
    const int lane = tid & 63, halfw = (tid >> 6) & 1;
    for (int it = 0; it < 128; ++it) {
        const int s = it*2 + sb;
        const float4* xrow4 = (const float4*)(&xs[s*40]);
        float acc = b0j;
        #pragma unroll
        for (int q = 0; q < 10; ++q) {
            const float4 v = xrow4[q];
            acc = fmaf(v.x, w0c[q*4+0], acc); acc = fmaf(v.y, w0c[q*4+1], acc);
            acc = fmaf(v.z, w0c[q*4+2], acc); acc = fmaf(v.w, w0c[q*4+3], acc);
        }
        h0s[sb][j] = fmaxf(acc, 0.f);
        __syncthreads();
        float acc1 = b1j;
        const float4* h4 = (const float4*)(&h0s[sb][0]);
        #pragma unroll
        for (int q = 0; q < 32; ++q) {
            const float4 v = h4[q];
            acc1 = fmaf(v.x, w1c[q*4+0], acc1); acc1 = fmaf(v.y, w1c[q*4+1], acc1);
            acc1 = fmaf(v.z, w1c[q*4+2], acc1); acc1 = fmaf(v.w, w1c[q*4+3], acc1);
        }
        const float hv = fmaxf(acc1, 0.f);
        float p0 = hv*w2r0, p1 = hv*w2r1, p2 = hv*w2r2;
        #pragma unroll
        for (int off = 32; off > 0; off >>= 1) {
            p0 += __shfl_down(p0, off); p1 += __shfl_down(p1, off); p2 += __shfl_down(p2, off);
        }
        if (lane == 0) { red[sb][halfw][0]=p0; red[sb][halfw][1]=p1; red[sb][halfw][2]=p2; }
        __syncthreads();
        if (tid == sb*128) {
            const float r0 = red[sb][0][0]+red[sb][1][0]+b20;
            const float r1 = red[sb][0][1]+red[sb][1][1]+b21;
            const float r2 = red[sb][0][2]+red[sb][1][2]+b22;
            const float wgt = wts[s];
            rgbacc[sb*3+0] += wgt / (1.f + expf(-r0));
            rgbacc[sb*3+1] += wgt / (1.f + expf(-r1));
            rgbacc[sb*3+2] += wgt / (1.f + expf(-r2));
        }
    }
    __syncthreads();
    if (tid < 3) out[r*3 + tid] = rgbacc[tid] + rgbacc[3 + tid] + ainv_sh;
}

extern "C" void kernel_launch(void* const* d_in, const int* in_sizes, int n_in,
                              void* d_out, int out_size, void* d_ws, size_t ws_size,
                              hipStream_t stream)
{
    const float* rays_o = (const float*)d_in[0];
    const float* rays_d = (const float*)d_in[1];
    const float* dens   = (const float*)d_in[2];
    const float* k0     = (const float*)d_in[3];
    const float* w0     = (const float*)d_in[4];
    const float* b0     = (const float*)d_in[5];
    const float* w1     = (const float*)d_in[6];
    const float* b1     = (const float*)d_in[7];
    const float* w2     = (const float*)d_in[8];
    const float* b2     = (const float*)d_in[9];
    float* out = (float*)d_out;
    const int N = in_sizes[0] / 3;

    if (ws_size >= WS_NEED) {
        unsigned short* gp  = (unsigned short*)d_ws;
        unsigned short* wpk = (unsigned short*)((char*)d_ws + W0P_OFF);
        repack_all<<<dim3(4011), dim3(256), 0, stream>>>(dens, k0, w0, w1, w2, gp, wpk);
        dvgo_mfma<<<dim3(N), dim3(256), 0, stream>>>(rays_o, rays_d, w0, b0, b1, b2,
                                                     gp, wpk, out);
    } else {
        dvgo_render<<<dim3(N), dim3(256), 0, stream>>>(rays_o, rays_d, dens, k0,
                                                       w0, b0, w1, b1, w2, b2, out);
    }
}